// Round 1
// baseline (922.391 us; speedup 1.0000x reference)
//
#include <hip/hip_runtime.h>
#include <hip/hip_bf16.h>
#include <math.h>

#define NN 384
#define HD 768
#define EE 12288
#define NEXPERT 8
#define TOPK 2
#define NLAYER 3
#define NHEADS 4
#define NMASK 38

__device__ __forceinline__ float gelu_f(float x) {
    return x * 0.5f * (1.f + erff(x * 0.70710678118654752440f));
}

// ---------------------------------------------------------------- elementwise
__global__ void k_xm(const float* __restrict__ a, const float* __restrict__ b,
                     float* __restrict__ xm, int n) {
    int i = blockIdx.x * 256 + threadIdx.x;
    if (i < n) xm[i] = 0.5f * (a[i] + b[i]);
}

__global__ void k_mask(const int* __restrict__ mask_idx, const float* __restrict__ mt,
                       float* __restrict__ xm) {
    int i = blockIdx.x * 256 + threadIdx.x;
    if (i >= NMASK * HD) return;
    int m = i / HD, j = i % HD;
    xm[(size_t)mask_idx[m] * HD + j] = mt[j];
}

__global__ void k_copy_h(const float* __restrict__ h, float* __restrict__ out) {
    int i = blockIdx.x * 256 + threadIdx.x;
    if (i < NN * HD) out[1 + i] = h[i];
}

// ---------------------------------------------------------------- gating
__global__ __launch_bounds__(256) void k_gate(const float* __restrict__ xm,
        const float* __restrict__ gW, const float* __restrict__ gb,
        int* __restrict__ topi, float* __restrict__ topw) {
    int n = blockIdx.x;
    int grp = threadIdx.x >> 5;      // expert 0..7
    int l32 = threadIdx.x & 31;
    float p = 0.f;
    for (int dd = l32; dd < HD; dd += 32) p += xm[(size_t)n * HD + dd] * gW[dd * NEXPERT + grp];
#pragma unroll
    for (int m = 1; m < 32; m <<= 1) p += __shfl_xor(p, m, 32);
    __shared__ float logits[NEXPERT];
    if (l32 == 0) logits[grp] = p + gb[grp];
    __syncthreads();
    if (threadIdx.x == 0) {
        float mx = logits[0];
#pragma unroll
        for (int e = 1; e < NEXPERT; e++) mx = fmaxf(mx, logits[e]);
        float sm[NEXPERT]; float s = 0.f;
#pragma unroll
        for (int e = 0; e < NEXPERT; e++) { sm[e] = expf(logits[e] - mx); s += sm[e]; }
#pragma unroll
        for (int e = 0; e < NEXPERT; e++) sm[e] /= s;
        int i0 = 0; float b0 = sm[0];
#pragma unroll
        for (int e = 1; e < NEXPERT; e++) if (sm[e] > b0) { b0 = sm[e]; i0 = e; }
        int i1 = -1; float b1v = -1.f;
#pragma unroll
        for (int e = 0; e < NEXPERT; e++) if (e != i0 && sm[e] > b1v) { b1v = sm[e]; i1 = e; }
        float ssum = b0 + b1v;
        topi[n * 2] = i0; topi[n * 2 + 1] = i1;
        topw[n * 2] = b0 / ssum; topw[n * 2 + 1] = b1v / ssum;
    }
}

// ---------------------------------------------------------------- expert grouping
__global__ void k_count_assign(const int* __restrict__ topi, int* __restrict__ ecnt) {
    int a = blockIdx.x * 256 + threadIdx.x;
    if (a < NN * TOPK) atomicAdd(&ecnt[topi[a]], 1);
}

__global__ void k_scan_experts(const int* __restrict__ ecnt, int* __restrict__ estart) {
    if (threadIdx.x == 0 && blockIdx.x == 0) {
        int s = 0;
        for (int e = 0; e < NEXPERT; e++) { estart[e] = s; s += ecnt[e]; }
        estart[NEXPERT] = s;
    }
}

__global__ void k_rank_assign(const int* __restrict__ topi, const int* __restrict__ estart,
                              int* __restrict__ posArr, int* __restrict__ eofpos,
                              int* __restrict__ rowlist) {
    int a = blockIdx.x * 256 + threadIdx.x;
    if (a >= NN * TOPK) return;
    int e = topi[a]; int rank = 0;
    for (int a2 = 0; a2 < a; a2++) rank += (topi[a2] == e) ? 1 : 0;
    int p = estart[e] + rank;
    posArr[a] = p; eofpos[p] = e; rowlist[p] = a >> 1;
}

// ---------------------------------------------------------------- edge sort (by dst, stable)
__global__ void k_count_edges(const int* __restrict__ dst, int* __restrict__ dcount) {
    int e = blockIdx.x * 256 + threadIdx.x;
    if (e < EE) atomicAdd(&dcount[dst[e]], 1);
}

__global__ void k_scan_nodes(const int* __restrict__ dcount, int* __restrict__ nstart) {
    if (threadIdx.x == 0 && blockIdx.x == 0) {
        int s = 0;
        for (int n = 0; n < NN; n++) { nstart[n] = s; s += dcount[n]; }
        nstart[NN] = s;
    }
}

__global__ __launch_bounds__(256) void k_rank_edges(const int* __restrict__ dst,
        const int* __restrict__ nstart, int* __restrict__ esorted) {
    __shared__ int ds[256];
    int e = blockIdx.x * 256 + threadIdx.x;
    int de = dst[e];
    int rank = 0;
    for (int c0 = 0; c0 <= (int)blockIdx.x * 256; c0 += 256) {
        ds[threadIdx.x] = dst[c0 + threadIdx.x];
        __syncthreads();
        int lim = e - c0; if (lim > 256) lim = 256;
        for (int i = 0; i < lim; i++) rank += (ds[i] == de) ? 1 : 0;
        __syncthreads();
    }
    esorted[nstart[de] + rank] = e;
}

// ---------------------------------------------------------------- generic tiled f32 GEMM
// C[M,Ncols] = A @ B ; optional A-row gather + per-z (expert) segmentation.
__global__ __launch_bounds__(256) void k_gemm(
        const float* __restrict__ A, const float* __restrict__ B, float* __restrict__ C,
        int M, int K, int lda, int ldb, int ldc, long strideB,
        const int* __restrict__ rowsA, const int* __restrict__ Ms,
        const int* __restrict__ rowStarts) {
    int z = blockIdx.z;
    int Meff = Ms ? Ms[z] : M;
    int row0 = blockIdx.y * 64;
    if (row0 >= Meff) return;
    int col0 = blockIdx.x * 64;
    const float* Bz = B + (long)z * strideB;
    int rowbase = rowStarts ? rowStarts[z] : 0;
    float* Cz = C + (size_t)rowbase * ldc;
    const int* rz = rowsA ? (rowsA + rowbase) : nullptr;
    const float* Az = (rowsA || !rowStarts) ? A : (A + (size_t)rowbase * lda);

    __shared__ float As[64][17];
    __shared__ float Bs[16][68];
    int tid = threadIdx.x;
    int ar = tid >> 2, ac = (tid & 3) << 2;
    int br = tid >> 4, bc = (tid & 15) << 2;
    int tx = tid & 15, ty = tid >> 4;
    float acc[4][4] = {};
    for (int k0 = 0; k0 < K; k0 += 16) {
        float4 av = make_float4(0.f, 0.f, 0.f, 0.f);
        int grow = row0 + ar;
        if (grow < Meff) {
            int srow = rz ? rz[grow] : grow;
            av = *reinterpret_cast<const float4*>(Az + (size_t)srow * lda + k0 + ac);
        }
        As[ar][ac] = av.x; As[ar][ac + 1] = av.y; As[ar][ac + 2] = av.z; As[ar][ac + 3] = av.w;
        float4 bv = *reinterpret_cast<const float4*>(Bz + (size_t)(k0 + br) * ldb + col0 + bc);
        Bs[br][bc] = bv.x; Bs[br][bc + 1] = bv.y; Bs[br][bc + 2] = bv.z; Bs[br][bc + 3] = bv.w;
        __syncthreads();
#pragma unroll
        for (int kk = 0; kk < 16; kk++) {
            float a0 = As[ty * 4 + 0][kk], a1 = As[ty * 4 + 1][kk];
            float a2 = As[ty * 4 + 2][kk], a3 = As[ty * 4 + 3][kk];
            float b0 = Bs[kk][tx * 4 + 0], b1 = Bs[kk][tx * 4 + 1];
            float b2 = Bs[kk][tx * 4 + 2], b3 = Bs[kk][tx * 4 + 3];
            acc[0][0] += a0 * b0; acc[0][1] += a0 * b1; acc[0][2] += a0 * b2; acc[0][3] += a0 * b3;
            acc[1][0] += a1 * b0; acc[1][1] += a1 * b1; acc[1][2] += a1 * b2; acc[1][3] += a1 * b3;
            acc[2][0] += a2 * b0; acc[2][1] += a2 * b1; acc[2][2] += a2 * b2; acc[2][3] += a2 * b3;
            acc[3][0] += a3 * b0; acc[3][1] += a3 * b1; acc[3][2] += a3 * b2; acc[3][3] += a3 * b3;
        }
        __syncthreads();
    }
#pragma unroll
    for (int i = 0; i < 4; i++) {
        int r = row0 + ty * 4 + i;
        if (r < Meff) {
            float* cp = Cz + (size_t)r * ldc + col0 + tx * 4;
            cp[0] = acc[i][0]; cp[1] = acc[i][1]; cp[2] = acc[i][2]; cp[3] = acc[i][3];
        }
    }
}

// ---------------------------------------------------------------- expert LN+GELU
__global__ __launch_bounds__(256) void k_ln_gelu(const float* __restrict__ t1,
        float* __restrict__ eh, const float* __restrict__ b1, const float* __restrict__ g,
        const float* __restrict__ be, const int* __restrict__ eofpos) {
    int row = blockIdx.x;
    int e = eofpos[row];
    int tid = threadIdx.x;
    __shared__ float rA[4], rB[4];
    float v[3]; float s1 = 0.f, s2 = 0.f;
#pragma unroll
    for (int r = 0; r < 3; r++) {
        int c = r * 256 + tid;
        float x = t1[(size_t)row * HD + c] + b1[e * HD + c];
        v[r] = x; s1 += x; s2 += x * x;
    }
#pragma unroll
    for (int m = 1; m < 64; m <<= 1) { s1 += __shfl_xor(s1, m); s2 += __shfl_xor(s2, m); }
    int wave = tid >> 6, lane = tid & 63;
    if (lane == 0) { rA[wave] = s1; rB[wave] = s2; }
    __syncthreads();
    float S1 = rA[0] + rA[1] + rA[2] + rA[3];
    float S2 = rB[0] + rB[1] + rB[2] + rB[3];
    float mean = S1 * (1.f / HD);
    float var = S2 * (1.f / HD) - mean * mean;
    float rstd = rsqrtf(var + 1e-5f);
#pragma unroll
    for (int r = 0; r < 3; r++) {
        int c = r * 256 + tid;
        float zn = (v[r] - mean) * rstd * g[e * HD + c] + be[e * HD + c];
        eh[(size_t)row * HD + c] = gelu_f(zn);
    }
}

__global__ void k_combine_moe(const float* __restrict__ eo, const float* __restrict__ b2,
        const int* __restrict__ topi, const float* __restrict__ topw,
        const int* __restrict__ posArr, float* __restrict__ h) {
    int n = blockIdx.x;
    int tid = threadIdx.x;
    int e0 = topi[n * 2], e1 = topi[n * 2 + 1];
    float w0 = topw[n * 2], w1 = topw[n * 2 + 1];
    int p0 = posArr[n * 2], p1 = posArr[n * 2 + 1];
    for (int j = tid; j < HD; j += 256) {
        float v0 = eo[(size_t)p0 * HD + j] + b2[e0 * HD + j];
        float v1 = eo[(size_t)p1 * HD + j] + b2[e1 * HD + j];
        h[(size_t)n * HD + j] = w0 * v0 + w1 * v1;
    }
}

// ---------------------------------------------------------------- GAT
__global__ __launch_bounds__(256) void k_el_er(const float* __restrict__ f,
        const float* __restrict__ al, const float* __restrict__ ar,
        float* __restrict__ el, float* __restrict__ er) {
    int n = blockIdx.x;
    int hd = threadIdx.x >> 6, lane = threadIdx.x & 63;
    const float* fr = f + ((size_t)n * NHEADS + hd) * HD;
    float pl = 0.f, pr = 0.f;
    for (int j = lane; j < HD; j += 64) {
        float fv = fr[j];
        pl += fv * al[hd * HD + j];
        pr += fv * ar[hd * HD + j];
    }
#pragma unroll
    for (int m = 1; m < 64; m <<= 1) { pl += __shfl_xor(pl, m); pr += __shfl_xor(pr, m); }
    if (lane == 0) { el[n * NHEADS + hd] = pl; er[n * NHEADS + hd] = pr; }
}

__global__ __launch_bounds__(256) void k_gat_agg(const float* __restrict__ f,
        const float* __restrict__ el, const float* __restrict__ er,
        const int* __restrict__ src, const int* __restrict__ esorted,
        const int* __restrict__ nstart, const float* __restrict__ gb,
        float* __restrict__ hout) {
    int n = blockIdx.x;
    int s0 = nstart[n], cnt = nstart[n + 1] - s0;
    int tid = threadIdx.x;
    __shared__ float red[4][NHEADS];
    __shared__ float emax_s[NHEADS], den_s[NHEADS];
    __shared__ float alpha_s[256][NHEADS];
    __shared__ int sn_s[256];
    float ern[NHEADS];
#pragma unroll
    for (int hd = 0; hd < NHEADS; hd++) ern[hd] = er[n * NHEADS + hd];
    int wave = tid >> 6, lane = tid & 63;

    // pass 1: per-head max
    float mx[NHEADS] = { -1e30f, -1e30f, -1e30f, -1e30f };
    for (int t = tid; t < cnt; t += 256) {
        int e = esorted[s0 + t]; int sn = src[e];
#pragma unroll
        for (int hd = 0; hd < NHEADS; hd++) {
            float v = el[sn * NHEADS + hd] + ern[hd];
            v = (v >= 0.f) ? v : 0.2f * v;
            mx[hd] = fmaxf(mx[hd], v);
        }
    }
#pragma unroll
    for (int hd = 0; hd < NHEADS; hd++) {
#pragma unroll
        for (int m = 1; m < 64; m <<= 1) mx[hd] = fmaxf(mx[hd], __shfl_xor(mx[hd], m));
    }
    if (lane == 0) { for (int hd = 0; hd < NHEADS; hd++) red[wave][hd] = mx[hd]; }
    __syncthreads();
    if (tid == 0) {
#pragma unroll
        for (int hd = 0; hd < NHEADS; hd++)
            emax_s[hd] = fmaxf(fmaxf(red[0][hd], red[1][hd]), fmaxf(red[2][hd], red[3][hd]));
    }
    __syncthreads();
    // pass 2: denominators
    float sm[NHEADS] = { 0.f, 0.f, 0.f, 0.f };
    for (int t = tid; t < cnt; t += 256) {
        int e = esorted[s0 + t]; int sn = src[e];
#pragma unroll
        for (int hd = 0; hd < NHEADS; hd++) {
            float v = el[sn * NHEADS + hd] + ern[hd];
            v = (v >= 0.f) ? v : 0.2f * v;
            sm[hd] += expf(v - emax_s[hd]);
        }
    }
#pragma unroll
    for (int hd = 0; hd < NHEADS; hd++) {
#pragma unroll
        for (int m = 1; m < 64; m <<= 1) sm[hd] += __shfl_xor(sm[hd], m);
    }
    __syncthreads();
    if (lane == 0) { for (int hd = 0; hd < NHEADS; hd++) red[wave][hd] = sm[hd]; }
    __syncthreads();
    if (tid == 0) {
#pragma unroll
        for (int hd = 0; hd < NHEADS; hd++)
            den_s[hd] = red[0][hd] + red[1][hd] + red[2][hd] + red[3][hd];
    }
    __syncthreads();
    // pass 3: weighted aggregate
    float acc[NHEADS][3] = {};
    for (int c0 = 0; c0 < cnt; c0 += 256) {
        int t = c0 + tid;
        if (t < cnt) {
            int e = esorted[s0 + t]; int sn = src[e];
            sn_s[tid] = sn;
#pragma unroll
            for (int hd = 0; hd < NHEADS; hd++) {
                float v = el[sn * NHEADS + hd] + ern[hd];
                v = (v >= 0.f) ? v : 0.2f * v;
                alpha_s[tid][hd] = expf(v - emax_s[hd]) / fmaxf(den_s[hd], 1e-9f);
            }
        }
        __syncthreads();
        int cm = cnt - c0; if (cm > 256) cm = 256;
        for (int i = 0; i < cm; i++) {
            int sn = sn_s[i];
            const float* fr = f + (size_t)sn * (NHEADS * HD);
#pragma unroll
            for (int hd = 0; hd < NHEADS; hd++) {
                float a = alpha_s[i][hd];
#pragma unroll
                for (int r = 0; r < 3; r++) acc[hd][r] += a * fr[hd * HD + r * 256 + tid];
            }
        }
        __syncthreads();
    }
#pragma unroll
    for (int r = 0; r < 3; r++) {
        int j = r * 256 + tid;
        float s = 0.f;
#pragma unroll
        for (int hd = 0; hd < NHEADS; hd++) s += acc[hd][r] + gb[hd * HD + j];
        hout[(size_t)n * HD + j] = 0.25f * s;
    }
}

// ---------------------------------------------------------------- decoder / recon
__global__ __launch_bounds__(256) void k_dec(const float* __restrict__ h,
        const int* __restrict__ mask_idx, const float* __restrict__ W1,
        const float* __restrict__ b1, const float* __restrict__ g,
        const float* __restrict__ be, const float* __restrict__ W2,
        const float* __restrict__ b2, const float* __restrict__ ft,
        const float* __restrict__ fi, float* __restrict__ rec_part) {
    int m = blockIdx.x >> 1;
    int d = blockIdx.x & 1;
    int node = mask_idx[m];
    int tid = threadIdx.x;
    __shared__ float hrow[HD];
    __shared__ float zz[HD];
    __shared__ float rA[4], rB[4], rC[4];
    for (int j = tid; j < HD; j += 256) hrow[j] = h[(size_t)node * HD + j];
    __syncthreads();
    const float* W1d = W1 + (size_t)d * HD * HD;
    float v[3] = { 0.f, 0.f, 0.f };
    for (int dd = 0; dd < HD; dd++) {
        float hv = hrow[dd];
        const float* wrow = W1d + (size_t)dd * HD;
#pragma unroll
        for (int r = 0; r < 3; r++) v[r] += hv * wrow[r * 256 + tid];
    }
    float s1 = 0.f, s2 = 0.f;
#pragma unroll
    for (int r = 0; r < 3; r++) {
        v[r] += b1[d * HD + r * 256 + tid];
        s1 += v[r]; s2 += v[r] * v[r];
    }
#pragma unroll
    for (int mm = 1; mm < 64; mm <<= 1) { s1 += __shfl_xor(s1, mm); s2 += __shfl_xor(s2, mm); }
    int wave = tid >> 6, lane = tid & 63;
    if (lane == 0) { rA[wave] = s1; rB[wave] = s2; }
    __syncthreads();
    float S1 = rA[0] + rA[1] + rA[2] + rA[3];
    float S2 = rB[0] + rB[1] + rB[2] + rB[3];
    float mean = S1 * (1.f / HD);
    float var = S2 * (1.f / HD) - mean * mean;
    float rstd = rsqrtf(var + 1e-5f);
#pragma unroll
    for (int r = 0; r < 3; r++) {
        int c = r * 256 + tid;
        float zn = (v[r] - mean) * rstd * g[d * HD + c] + be[d * HD + c];
        zz[c] = gelu_f(zn);
    }
    __syncthreads();
    const float* W2d = W2 + (size_t)d * HD * HD;
    const float* orig = (d == 0 ? ft : fi) + (size_t)node * HD;
    float rec[3] = { 0.f, 0.f, 0.f };
    for (int dd = 0; dd < HD; dd++) {
        float zv = zz[dd];
        const float* wrow = W2d + (size_t)dd * HD;
#pragma unroll
        for (int r = 0; r < 3; r++) rec[r] += zv * wrow[r * 256 + tid];
    }
    float pro = 0.f, prr = 0.f, poo = 0.f;
#pragma unroll
    for (int r = 0; r < 3; r++) {
        int c = r * 256 + tid;
        float rv = rec[r] + b2[d * HD + c];
        float o = orig[c];
        pro += rv * o; prr += rv * rv; poo += o * o;
    }
#pragma unroll
    for (int mm = 1; mm < 64; mm <<= 1) {
        pro += __shfl_xor(pro, mm); prr += __shfl_xor(prr, mm); poo += __shfl_xor(poo, mm);
    }
    if (lane == 0) { rA[wave] = pro; rB[wave] = prr; rC[wave] = poo; }
    __syncthreads();
    if (tid == 0) {
        float P = rA[0] + rA[1] + rA[2] + rA[3];
        float R = rB[0] + rB[1] + rB[2] + rB[3];
        float O = rC[0] + rC[1] + rC[2] + rC[3];
        float denom = fmaxf(sqrtf(R) * sqrtf(O), 1e-8f);
        float cosv = P / denom;
        float t = 1.f - cosv;
        rec_part[blockIdx.x] = (t * t) * (1.f / (float)NMASK);
    }
}

// ---------------------------------------------------------------- SPD loss
__global__ __launch_bounds__(256) void k_spd(const float* __restrict__ pa,
        const float* __restrict__ pb, const float* __restrict__ b1,
        const float* __restrict__ g, const float* __restrict__ be,
        const float* __restrict__ w2, const float* __restrict__ b2,
        const float* __restrict__ spd, float* __restrict__ partials) {
    __shared__ float pa_s[HD], b1_s[HD], g_s[HD], be_s[HD], w2_s[HD];
    __shared__ float wsum[4];
    int i = blockIdx.x;
    for (int t = threadIdx.x; t < HD; t += 256) {
        pa_s[t] = pa[(size_t)i * HD + t];
        b1_s[t] = b1[t]; g_s[t] = g[t]; be_s[t] = be[t]; w2_s[t] = w2[t];
    }
    __syncthreads();
    int wave = threadIdx.x >> 6, lane = threadIdx.x & 63;
    float bacc = 0.f;
    float b2v = b2[0];
    for (int j = wave; j < NN; j += 4) {
        const float* pbj = pb + (size_t)j * HD;
        float z[12];
        float s1 = 0.f, s2 = 0.f;
#pragma unroll
        for (int r = 0; r < 12; r++) {
            int e = r * 64 + lane;
            float v = pa_s[e] + pbj[e] + b1_s[e];
            z[r] = v; s1 += v; s2 += v * v;
        }
#pragma unroll
        for (int m = 1; m < 64; m <<= 1) { s1 += __shfl_xor(s1, m); s2 += __shfl_xor(s2, m); }
        float mean = s1 * (1.f / HD);
        float var = s2 * (1.f / HD) - mean * mean;
        float rstd = rsqrtf(var + 1e-5f);
        float dot = 0.f;
#pragma unroll
        for (int r = 0; r < 12; r++) {
            int e = r * 64 + lane;
            float zn = (z[r] - mean) * rstd * g_s[e] + be_s[e];
            dot += gelu_f(zn) * w2_s[e];
        }
#pragma unroll
        for (int m = 1; m < 64; m <<= 1) dot += __shfl_xor(dot, m);
        if (lane == 0) {
            float d = (dot + b2v) - spd[(size_t)i * NN + j];
            bacc += d * d;
        }
    }
    if (lane == 0) wsum[wave] = bacc;
    __syncthreads();
    if (threadIdx.x == 0) partials[i] = wsum[0] + wsum[1] + wsum[2] + wsum[3];
}

__global__ void k_final(const float* __restrict__ rec_part,
                        const float* __restrict__ spd_part, float* __restrict__ out) {
    if (blockIdx.x == 0 && threadIdx.x == 0) {
        float rec = 0.f;
        for (int i = 0; i < 2 * NMASK; i++) rec += rec_part[i];
        float sp = 0.f;
        for (int i = 0; i < NN; i++) sp += spd_part[i];
        out[0] = rec + 0.5f * (sp * (1.f / ((float)NN * (float)NN)));
    }
}

// ================================================================ host
extern "C" void kernel_launch(void* const* d_in, const int* in_sizes, int n_in,
                              void* d_out, int out_size, void* d_ws, size_t ws_size,
                              hipStream_t stream) {
    const float* feat_text = (const float*)d_in[0];
    const float* feat_image = (const float*)d_in[1];
    const float* spd_matrix = (const float*)d_in[2];
    const int*   src       = (const int*)d_in[3];
    const int*   dst       = (const int*)d_in[4];
    const int*   mask_idx  = (const int*)d_in[5];
    const float* mask_token = (const float*)d_in[6];
    const float* gate_W = (const float*)d_in[7];
    const float* gate_b = (const float*)d_in[8];
    const float* exp_W1 = (const float*)d_in[9];
    const float* exp_b1 = (const float*)d_in[10];
    const float* exp_g1 = (const float*)d_in[11];
    const float* exp_be1 = (const float*)d_in[12];
    const float* exp_W2 = (const float*)d_in[13];
    const float* exp_b2 = (const float*)d_in[14];
    const float* gat_W  = (const float*)d_in[15];
    const float* gat_al = (const float*)d_in[16];
    const float* gat_ar = (const float*)d_in[17];
    const float* gat_b  = (const float*)d_in[18];
    const float* dec_W1 = (const float*)d_in[19];
    const float* dec_b1 = (const float*)d_in[20];
    const float* dec_g  = (const float*)d_in[21];
    const float* dec_be = (const float*)d_in[22];
    const float* dec_W2 = (const float*)d_in[23];
    const float* dec_b2 = (const float*)d_in[24];
    const float* spd_W1 = (const float*)d_in[25];
    const float* spd_b1 = (const float*)d_in[26];
    const float* spd_g  = (const float*)d_in[27];
    const float* spd_be = (const float*)d_in[28];
    const float* spd_W2 = (const float*)d_in[29];
    const float* spd_b2 = (const float*)d_in[30];
    (void)in_sizes; (void)n_in; (void)ws_size; (void)out_size;

    float* ws = (float*)d_ws;
    size_t off = 0;
    auto alloc = [&](size_t nfl) { float* p = ws + off; off += (nfl + 3) & ~(size_t)3; return p; };
    float* xm = alloc((size_t)NN * HD);
    float* hA = alloc((size_t)NN * HD);
    float* hB = alloc((size_t)NN * HD);
    float* t1 = alloc((size_t)NN * TOPK * HD);
    float* eh = alloc((size_t)NN * TOPK * HD);
    float* eo = alloc((size_t)NN * TOPK * HD);
    float* fbuf = alloc((size_t)NN * NHEADS * HD);
    float* el = alloc(NN * NHEADS);
    float* er = alloc(NN * NHEADS);
    float* pa = alloc((size_t)NN * HD);
    float* pb = alloc((size_t)NN * HD);
    float* topw = alloc(NN * TOPK);
    float* rec_part = alloc(2 * NMASK + 4);
    float* spd_part = alloc(NN);
    int* topi    = (int*)alloc(NN * TOPK);
    int* ecnt    = (int*)alloc(16);
    int* estart  = (int*)alloc(16);
    int* posArr  = (int*)alloc(NN * TOPK);
    int* eofpos  = (int*)alloc(NN * TOPK);
    int* rowlist = (int*)alloc(NN * TOPK);
    int* dcount  = (int*)alloc(NN);
    int* nstart  = (int*)alloc(NN + 4);
    int* esorted = (int*)alloc(EE);

    hipMemsetAsync(ecnt, 0, 16 * sizeof(int), stream);
    hipMemsetAsync(dcount, 0, NN * sizeof(int), stream);

    // xm = 0.5*(ft+fi); mask rows
    k_xm<<<dim3((NN * HD + 255) / 256), dim3(256), 0, stream>>>(feat_text, feat_image, xm, NN * HD);
    k_mask<<<dim3((NMASK * HD + 255) / 256), dim3(256), 0, stream>>>(mask_idx, mask_token, xm);

    // gating + expert grouping
    k_gate<<<dim3(NN), dim3(256), 0, stream>>>(xm, gate_W, gate_b, topi, topw);
    k_count_assign<<<dim3(3), dim3(256), 0, stream>>>(topi, ecnt);
    k_scan_experts<<<dim3(1), dim3(64), 0, stream>>>(ecnt, estart);
    k_rank_assign<<<dim3(3), dim3(256), 0, stream>>>(topi, estart, posArr, eofpos, rowlist);

    // edge sort (dst-stable)
    k_count_edges<<<dim3(EE / 256), dim3(256), 0, stream>>>(dst, dcount);
    k_scan_nodes<<<dim3(1), dim3(64), 0, stream>>>(dcount, nstart);
    k_rank_edges<<<dim3(EE / 256), dim3(256), 0, stream>>>(dst, nstart, esorted);

    // experts: t1 = gather(xm) @ W1[e]  (per-expert segments)
    k_gemm<<<dim3(HD / 64, 6, NEXPERT), dim3(256), 0, stream>>>(
        xm, exp_W1, t1, 0, HD, HD, HD, HD, (long)HD * HD, rowlist, ecnt, estart);
    k_ln_gelu<<<dim3(NN * TOPK), dim3(256), 0, stream>>>(t1, eh, exp_b1, exp_g1, exp_be1, eofpos);
    k_gemm<<<dim3(HD / 64, 6, NEXPERT), dim3(256), 0, stream>>>(
        eh, exp_W2, eo, 0, HD, HD, HD, HD, (long)HD * HD, nullptr, ecnt, estart);
    k_combine_moe<<<dim3(NN), dim3(256), 0, stream>>>(eo, exp_b2, topi, topw, posArr, hA);

    // GAT layers
    float* hcur = hA;
    float* hnxt = hB;
    for (int l = 0; l < NLAYER; l++) {
        k_gemm<<<dim3(NHEADS * HD / 64, NN / 64, 1), dim3(256), 0, stream>>>(
            hcur, gat_W + (size_t)l * HD * NHEADS * HD, fbuf,
            NN, HD, HD, NHEADS * HD, NHEADS * HD, 0, nullptr, nullptr, nullptr);
        k_el_er<<<dim3(NN), dim3(256), 0, stream>>>(
            fbuf, gat_al + (size_t)l * NHEADS * HD, gat_ar + (size_t)l * NHEADS * HD, el, er);
        k_gat_agg<<<dim3(NN), dim3(256), 0, stream>>>(
            fbuf, el, er, src, esorted, nstart, gat_b + (size_t)l * NHEADS * HD, hnxt);
        float* t = hcur; hcur = hnxt; hnxt = t;
    }

    // decoder recon loss
    k_dec<<<dim3(2 * NMASK), dim3(256), 0, stream>>>(
        hcur, mask_idx, dec_W1, dec_b1, dec_g, dec_be, dec_W2, dec_b2,
        feat_text, feat_image, rec_part);

    // SPD projections + loss
    k_gemm<<<dim3(HD / 64, NN / 64, 1), dim3(256), 0, stream>>>(
        hcur, spd_W1, pa, NN, HD, HD, HD, HD, 0, nullptr, nullptr, nullptr);
    k_gemm<<<dim3(HD / 64, NN / 64, 1), dim3(256), 0, stream>>>(
        hcur, spd_W1 + (size_t)HD * HD, pb, NN, HD, HD, HD, HD, 0, nullptr, nullptr, nullptr);
    k_spd<<<dim3(NN), dim3(256), 0, stream>>>(
        pa, pb, spd_b1, spd_g, spd_be, spd_W2, spd_b2, spd_matrix, spd_part);

    // finalize
    k_final<<<dim3(1), dim3(64), 0, stream>>>(rec_part, spd_part, (float*)d_out);
    k_copy_h<<<dim3((NN * HD + 255) / 256), dim3(256), 0, stream>>>(hcur, (float*)d_out);
}

// Round 2
// 571.607 us; speedup vs baseline: 1.6137x; 1.6137x over previous
//
#include <hip/hip_runtime.h>
#include <hip/hip_bf16.h>
#include <math.h>

#define NN 384
#define HD 768
#define EE 12288
#define NEXPERT 8
#define TOPK 2
#define NLAYER 3
#define NHEADS 4
#define NMASK 38

typedef __attribute__((ext_vector_type(8))) short short8v;
typedef __attribute__((ext_vector_type(4))) float f32x4;
typedef __attribute__((ext_vector_type(4))) int int4v;

__device__ __forceinline__ float gelu_f(float x) {
    return x * 0.5f * (1.f + erff(x * 0.70710678118654752440f));
}

__device__ __forceinline__ ushort f2bf(float x) {
    unsigned u = __float_as_uint(x);
    u += 0x7fffu + ((u >> 16) & 1u);
    return (ushort)(u >> 16);
}

// ---------------------------------------------------------------- elementwise
__global__ void k_xm(const float* __restrict__ a, const float* __restrict__ b,
                     float* __restrict__ xm, int n) {
    int i = blockIdx.x * 256 + threadIdx.x;
    if (i < n) xm[i] = 0.5f * (a[i] + b[i]);
}

__global__ void k_mask(const int* __restrict__ mask_idx, const float* __restrict__ mt,
                       float* __restrict__ xm) {
    int i = blockIdx.x * 256 + threadIdx.x;
    if (i >= NMASK * HD) return;
    int m = i / HD, j = i % HD;
    xm[(size_t)mask_idx[m] * HD + j] = mt[j];
}

__global__ void k_tobf(const float* __restrict__ in, ushort* __restrict__ out, int n4) {
    int i = blockIdx.x * 256 + threadIdx.x;
    if (i >= n4) return;
    float4 v = *reinterpret_cast<const float4*>(in + (size_t)i * 4);
    ushort r0 = f2bf(v.x), r1 = f2bf(v.y), r2 = f2bf(v.z), r3 = f2bf(v.w);
    uint2 p;
    p.x = (unsigned)r0 | ((unsigned)r1 << 16);
    p.y = (unsigned)r2 | ((unsigned)r3 << 16);
    *reinterpret_cast<uint2*>(out + (size_t)i * 4) = p;
}

__global__ void k_copy_h(const float* __restrict__ h, float* __restrict__ out) {
    int i = blockIdx.x * 256 + threadIdx.x;
    if (i < NN * HD) out[1 + i] = h[i];
}

// ---------------------------------------------------------------- transpose+convert weights
// in: f32 [z][K][N] -> out: bf16 [z][N][K]
__global__ __launch_bounds__(256) void k_transpose_bf(
        const float* __restrict__ in, ushort* __restrict__ out,
        int K, int N, long inStrideZ, long outStrideZ) {
    __shared__ float t[32][36];
    int z = blockIdx.z;
    const float* inz = in + (size_t)z * inStrideZ;
    ushort* outz = out + (size_t)z * outStrideZ;
    int n0 = blockIdx.x * 32, k0 = blockIdx.y * 32;
    int r = threadIdx.x >> 3, c4 = (threadIdx.x & 7) * 4;
    float4 v = *reinterpret_cast<const float4*>(inz + (size_t)(k0 + r) * N + n0 + c4);
    t[r][c4] = v.x; t[r][c4 + 1] = v.y; t[r][c4 + 2] = v.z; t[r][c4 + 3] = v.w;
    __syncthreads();
    int orow = n0 + r;
    uint2 p;
    ushort w0 = f2bf(t[c4 + 0][r]);
    ushort w1 = f2bf(t[c4 + 1][r]);
    ushort w2 = f2bf(t[c4 + 2][r]);
    ushort w3 = f2bf(t[c4 + 3][r]);
    p.x = (unsigned)w0 | ((unsigned)w1 << 16);
    p.y = (unsigned)w2 | ((unsigned)w3 << 16);
    *reinterpret_cast<uint2*>(outz + (size_t)orow * K + k0 + c4) = p;
}

// ---------------------------------------------------------------- gating
__global__ __launch_bounds__(256) void k_gate(const float* __restrict__ xm,
        const float* __restrict__ gW, const float* __restrict__ gb,
        int* __restrict__ topi, float* __restrict__ topw) {
    int n = blockIdx.x;
    int grp = threadIdx.x >> 5;
    int l32 = threadIdx.x & 31;
    float p = 0.f;
    for (int dd = l32; dd < HD; dd += 32) p += xm[(size_t)n * HD + dd] * gW[dd * NEXPERT + grp];
#pragma unroll
    for (int m = 1; m < 32; m <<= 1) p += __shfl_xor(p, m, 32);
    __shared__ float logits[NEXPERT];
    if (l32 == 0) logits[grp] = p + gb[grp];
    __syncthreads();
    if (threadIdx.x == 0) {
        float mx = logits[0];
#pragma unroll
        for (int e = 1; e < NEXPERT; e++) mx = fmaxf(mx, logits[e]);
        float sm[NEXPERT]; float s = 0.f;
#pragma unroll
        for (int e = 0; e < NEXPERT; e++) { sm[e] = expf(logits[e] - mx); s += sm[e]; }
#pragma unroll
        for (int e = 0; e < NEXPERT; e++) sm[e] /= s;
        int i0 = 0; float b0 = sm[0];
#pragma unroll
        for (int e = 1; e < NEXPERT; e++) if (sm[e] > b0) { b0 = sm[e]; i0 = e; }
        int i1 = -1; float b1v = -1.f;
#pragma unroll
        for (int e = 0; e < NEXPERT; e++) if (e != i0 && sm[e] > b1v) { b1v = sm[e]; i1 = e; }
        float ssum = b0 + b1v;
        topi[n * 2] = i0; topi[n * 2 + 1] = i1;
        topw[n * 2] = b0 / ssum; topw[n * 2 + 1] = b1v / ssum;
    }
}

// ---------------------------------------------------------------- expert grouping
__global__ void k_count_assign(const int* __restrict__ topi, int* __restrict__ ecnt) {
    int a = blockIdx.x * 256 + threadIdx.x;
    if (a < NN * TOPK) atomicAdd(&ecnt[topi[a]], 1);
}

__global__ void k_scan_experts(const int* __restrict__ ecnt, int* __restrict__ estart) {
    if (threadIdx.x == 0 && blockIdx.x == 0) {
        int s = 0;
        for (int e = 0; e < NEXPERT; e++) { estart[e] = s; s += ecnt[e]; }
        estart[NEXPERT] = s;
    }
}

__global__ void k_rank_assign(const int* __restrict__ topi, const int* __restrict__ estart,
                              int* __restrict__ posArr, int* __restrict__ eofpos,
                              int* __restrict__ rowlist) {
    int a = blockIdx.x * 256 + threadIdx.x;
    if (a >= NN * TOPK) return;
    int e = topi[a]; int rank = 0;
    for (int a2 = 0; a2 < a; a2++) rank += (topi[a2] == e) ? 1 : 0;
    int p = estart[e] + rank;
    posArr[a] = p; eofpos[p] = e; rowlist[p] = a >> 1;
}

// ---------------------------------------------------------------- edge sort (by dst, stable)
__global__ void k_count_edges(const int* __restrict__ dst, int* __restrict__ dcount) {
    int e = blockIdx.x * 256 + threadIdx.x;
    if (e < EE) atomicAdd(&dcount[dst[e]], 1);
}

__global__ void k_scan_nodes(const int* __restrict__ dcount, int* __restrict__ nstart) {
    if (threadIdx.x == 0 && blockIdx.x == 0) {
        int s = 0;
        for (int n = 0; n < NN; n++) { nstart[n] = s; s += dcount[n]; }
        nstart[NN] = s;
    }
}

__global__ __launch_bounds__(256) void k_rank_edges(const int* __restrict__ dst,
        const int* __restrict__ nstart, int* __restrict__ esorted) {
    __shared__ int ds[256];
    int e = blockIdx.x * 256 + threadIdx.x;
    int de = dst[e];
    int rank = 0;
    for (int c0 = 0; c0 <= (int)blockIdx.x * 256; c0 += 256) {
        ds[threadIdx.x] = dst[c0 + threadIdx.x];
        __syncthreads();
        int lim = e - c0; if (lim > 256) lim = 256;
        for (int i = 0; i < lim; i++) rank += (ds[i] == de) ? 1 : 0;
        __syncthreads();
    }
    esorted[nstart[de] + rank] = e;
}

// ---------------------------------------------------------------- bf16 MFMA GEMM
// C[M,N] = A(bf16,[M][lda], optional row-gather/segment) @ Bt(bf16,[N][K])^T
// 64x64 tile, BK=64, 4 waves 2x2, XOR-swizzled LDS (chunk ^= row&7).
__device__ __forceinline__ short8v ldfrag(const ushort* s, int r, int kb) {
    int c = kb ^ (r & 7);
    return *reinterpret_cast<const short8v*>(s + r * 64 + c * 8);
}

__global__ __launch_bounds__(256) void k_mfma_gemm(
        const ushort* __restrict__ A, const ushort* __restrict__ Bt, float* __restrict__ C,
        int M, int K, int lda, int ldc, long strideBt, long strideC,
        const int* __restrict__ rowsA, const int* __restrict__ Ms,
        const int* __restrict__ rowStarts) {
    int z = blockIdx.z;
    int Meff = Ms ? Ms[z] : M;
    int row0 = blockIdx.y * 64;
    if (row0 >= Meff) return;
    int col0 = blockIdx.x * 64;
    int rowbase = rowStarts ? rowStarts[z] : 0;
    const ushort* Btz = Bt + (size_t)z * strideBt;
    float* Cz = C + (size_t)rowbase * ldc + (size_t)z * strideC;
    const int* rz = rowsA ? (rowsA + rowbase) : nullptr;

    __shared__ ushort Asm[64 * 64];
    __shared__ ushort Bsm[64 * 64];

    int tid = threadIdx.x;
    int w = tid >> 6, lane = tid & 63;
    int wr = w >> 1, wc = w & 1;
    int l15 = lane & 15, lq = lane >> 4;

    f32x4 acc[2][2];
#pragma unroll
    for (int i = 0; i < 2; i++)
#pragma unroll
        for (int j = 0; j < 2; j++) acc[i][j] = (f32x4){0.f, 0.f, 0.f, 0.f};

    for (int k0 = 0; k0 < K; k0 += 64) {
#pragma unroll
        for (int ii = 0; ii < 2; ii++) {
            int i = tid + ii * 256;
            int r = i >> 3, c = i & 7;
            int cs = c ^ (r & 7);
            int4v av = (int4v){0, 0, 0, 0};
            int grow = row0 + r;
            if (grow < Meff) {
                int srow = rz ? rz[grow] : (rowbase + grow);
                av = *reinterpret_cast<const int4v*>(A + (size_t)srow * lda + k0 + c * 8);
            }
            *reinterpret_cast<int4v*>(&Asm[r * 64 + cs * 8]) = av;
            int4v bv = *reinterpret_cast<const int4v*>(Btz + (size_t)(col0 + r) * K + k0 + c * 8);
            *reinterpret_cast<int4v*>(&Bsm[r * 64 + cs * 8]) = bv;
        }
        __syncthreads();
#pragma unroll
        for (int ks = 0; ks < 2; ks++) {
            int kb = ks * 4 + lq;
            short8v a0 = ldfrag(Asm, wr * 32 + l15, kb);
            short8v a1 = ldfrag(Asm, wr * 32 + 16 + l15, kb);
            short8v b0 = ldfrag(Bsm, wc * 32 + l15, kb);
            short8v b1 = ldfrag(Bsm, wc * 32 + 16 + l15, kb);
            acc[0][0] = __builtin_amdgcn_mfma_f32_16x16x32_bf16(a0, b0, acc[0][0], 0, 0, 0);
            acc[0][1] = __builtin_amdgcn_mfma_f32_16x16x32_bf16(a0, b1, acc[0][1], 0, 0, 0);
            acc[1][0] = __builtin_amdgcn_mfma_f32_16x16x32_bf16(a1, b0, acc[1][0], 0, 0, 0);
            acc[1][1] = __builtin_amdgcn_mfma_f32_16x16x32_bf16(a1, b1, acc[1][1], 0, 0, 0);
        }
        __syncthreads();
    }
#pragma unroll
    for (int ai = 0; ai < 2; ai++)
#pragma unroll
        for (int bi = 0; bi < 2; bi++) {
            int rbase = row0 + wr * 32 + ai * 16 + (lq << 2);
            int cc = col0 + wc * 32 + bi * 16 + l15;
#pragma unroll
            for (int r = 0; r < 4; r++) {
                int rr = rbase + r;
                if (rr < Meff) Cz[(size_t)rr * ldc + cc] = acc[ai][bi][r];
            }
        }
}

// ---------------------------------------------------------------- expert LN+GELU -> bf16
__global__ __launch_bounds__(256) void k_ln_gelu(const float* __restrict__ t1,
        ushort* __restrict__ ehb, const float* __restrict__ b1, const float* __restrict__ g,
        const float* __restrict__ be, const int* __restrict__ eofpos) {
    int row = blockIdx.x;
    int e = eofpos[row];
    int tid = threadIdx.x;
    __shared__ float rA[4], rB[4];
    float v[3]; float s1 = 0.f, s2 = 0.f;
#pragma unroll
    for (int r = 0; r < 3; r++) {
        int c = r * 256 + tid;
        float x = t1[(size_t)row * HD + c] + b1[e * HD + c];
        v[r] = x; s1 += x; s2 += x * x;
    }
#pragma unroll
    for (int m = 1; m < 64; m <<= 1) { s1 += __shfl_xor(s1, m); s2 += __shfl_xor(s2, m); }
    int wave = tid >> 6, lane = tid & 63;
    if (lane == 0) { rA[wave] = s1; rB[wave] = s2; }
    __syncthreads();
    float S1 = rA[0] + rA[1] + rA[2] + rA[3];
    float S2 = rB[0] + rB[1] + rB[2] + rB[3];
    float mean = S1 * (1.f / HD);
    float var = S2 * (1.f / HD) - mean * mean;
    float rstd = rsqrtf(var + 1e-5f);
#pragma unroll
    for (int r = 0; r < 3; r++) {
        int c = r * 256 + tid;
        float zn = (v[r] - mean) * rstd * g[e * HD + c] + be[e * HD + c];
        ehb[(size_t)row * HD + c] = f2bf(gelu_f(zn));
    }
}

__global__ void k_combine_moe(const float* __restrict__ eo, const float* __restrict__ b2,
        const int* __restrict__ topi, const float* __restrict__ topw,
        const int* __restrict__ posArr, float* __restrict__ h, ushort* __restrict__ hb) {
    int n = blockIdx.x;
    int tid = threadIdx.x;
    int e0 = topi[n * 2], e1 = topi[n * 2 + 1];
    float w0 = topw[n * 2], w1 = topw[n * 2 + 1];
    int p0 = posArr[n * 2], p1 = posArr[n * 2 + 1];
    for (int j = tid; j < HD; j += 256) {
        float v0 = eo[(size_t)p0 * HD + j] + b2[e0 * HD + j];
        float v1 = eo[(size_t)p1 * HD + j] + b2[e1 * HD + j];
        float hv = w0 * v0 + w1 * v1;
        h[(size_t)n * HD + j] = hv;
        hb[(size_t)n * HD + j] = f2bf(hv);
    }
}

// ---------------------------------------------------------------- GAT
__global__ __launch_bounds__(256) void k_el_er(const float* __restrict__ f,
        const float* __restrict__ al, const float* __restrict__ ar,
        float* __restrict__ el, float* __restrict__ er) {
    int n = blockIdx.x;
    int hd = threadIdx.x >> 6, lane = threadIdx.x & 63;
    const float* fr = f + ((size_t)n * NHEADS + hd) * HD;
    float pl = 0.f, pr = 0.f;
    for (int j = lane; j < HD; j += 64) {
        float fv = fr[j];
        pl += fv * al[hd * HD + j];
        pr += fv * ar[hd * HD + j];
    }
#pragma unroll
    for (int m = 1; m < 64; m <<= 1) { pl += __shfl_xor(pl, m); pr += __shfl_xor(pr, m); }
    if (lane == 0) { el[n * NHEADS + hd] = pl; er[n * NHEADS + hd] = pr; }
}

__global__ __launch_bounds__(256) void k_gat_agg(const float* __restrict__ f,
        const float* __restrict__ el, const float* __restrict__ er,
        const int* __restrict__ src, const int* __restrict__ esorted,
        const int* __restrict__ nstart, const float* __restrict__ gb,
        float* __restrict__ hout, ushort* __restrict__ hb) {
    int n = blockIdx.x;
    int s0 = nstart[n], cnt = nstart[n + 1] - s0;
    int tid = threadIdx.x;
    __shared__ float red[4][NHEADS];
    __shared__ float emax_s[NHEADS], den_s[NHEADS];
    __shared__ float alpha_s[256][NHEADS];
    __shared__ int sn_s[256];
    float ern[NHEADS];
#pragma unroll
    for (int hd = 0; hd < NHEADS; hd++) ern[hd] = er[n * NHEADS + hd];
    int wave = tid >> 6, lane = tid & 63;

    float mx[NHEADS] = { -1e30f, -1e30f, -1e30f, -1e30f };
    for (int t = tid; t < cnt; t += 256) {
        int e = esorted[s0 + t]; int sn = src[e];
#pragma unroll
        for (int hd = 0; hd < NHEADS; hd++) {
            float v = el[sn * NHEADS + hd] + ern[hd];
            v = (v >= 0.f) ? v : 0.2f * v;
            mx[hd] = fmaxf(mx[hd], v);
        }
    }
#pragma unroll
    for (int hd = 0; hd < NHEADS; hd++) {
#pragma unroll
        for (int m = 1; m < 64; m <<= 1) mx[hd] = fmaxf(mx[hd], __shfl_xor(mx[hd], m));
    }
    if (lane == 0) { for (int hd = 0; hd < NHEADS; hd++) red[wave][hd] = mx[hd]; }
    __syncthreads();
    if (tid == 0) {
#pragma unroll
        for (int hd = 0; hd < NHEADS; hd++)
            emax_s[hd] = fmaxf(fmaxf(red[0][hd], red[1][hd]), fmaxf(red[2][hd], red[3][hd]));
    }
    __syncthreads();
    float sm[NHEADS] = { 0.f, 0.f, 0.f, 0.f };
    for (int t = tid; t < cnt; t += 256) {
        int e = esorted[s0 + t]; int sn = src[e];
#pragma unroll
        for (int hd = 0; hd < NHEADS; hd++) {
            float v = el[sn * NHEADS + hd] + ern[hd];
            v = (v >= 0.f) ? v : 0.2f * v;
            sm[hd] += expf(v - emax_s[hd]);
        }
    }
#pragma unroll
    for (int hd = 0; hd < NHEADS; hd++) {
#pragma unroll
        for (int m = 1; m < 64; m <<= 1) sm[hd] += __shfl_xor(sm[hd], m);
    }
    __syncthreads();
    if (lane == 0) { for (int hd = 0; hd < NHEADS; hd++) red[wave][hd] = sm[hd]; }
    __syncthreads();
    if (tid == 0) {
#pragma unroll
        for (int hd = 0; hd < NHEADS; hd++)
            den_s[hd] = red[0][hd] + red[1][hd] + red[2][hd] + red[3][hd];
    }
    __syncthreads();
    float acc[NHEADS][3] = {};
    for (int c0 = 0; c0 < cnt; c0 += 256) {
        int t = c0 + tid;
        if (t < cnt) {
            int e = esorted[s0 + t]; int sn = src[e];
            sn_s[tid] = sn;
#pragma unroll
            for (int hd = 0; hd < NHEADS; hd++) {
                float v = el[sn * NHEADS + hd] + ern[hd];
                v = (v >= 0.f) ? v : 0.2f * v;
                alpha_s[tid][hd] = expf(v - emax_s[hd]) / fmaxf(den_s[hd], 1e-9f);
            }
        }
        __syncthreads();
        int cm = cnt - c0; if (cm > 256) cm = 256;
        for (int i = 0; i < cm; i++) {
            int sn = sn_s[i];
            const float* fr = f + (size_t)sn * (NHEADS * HD);
#pragma unroll
            for (int hd = 0; hd < NHEADS; hd++) {
                float a = alpha_s[i][hd];
#pragma unroll
                for (int r = 0; r < 3; r++) acc[hd][r] += a * fr[hd * HD + r * 256 + tid];
            }
        }
        __syncthreads();
    }
#pragma unroll
    for (int r = 0; r < 3; r++) {
        int j = r * 256 + tid;
        float s = 0.f;
#pragma unroll
        for (int hd = 0; hd < NHEADS; hd++) s += acc[hd][r] + gb[hd * HD + j];
        float hv = 0.25f * s;
        hout[(size_t)n * HD + j] = hv;
        hb[(size_t)n * HD + j] = f2bf(hv);
    }
}

// ---------------------------------------------------------------- decoder / recon
__global__ __launch_bounds__(256) void k_dec(const float* __restrict__ h,
        const int* __restrict__ mask_idx, const float* __restrict__ W1,
        const float* __restrict__ b1, const float* __restrict__ g,
        const float* __restrict__ be, const float* __restrict__ W2,
        const float* __restrict__ b2, const float* __restrict__ ft,
        const float* __restrict__ fi, float* __restrict__ rec_part) {
    int m = blockIdx.x >> 1;
    int d = blockIdx.x & 1;
    int node = mask_idx[m];
    int tid = threadIdx.x;
    __shared__ float hrow[HD];
    __shared__ float zz[HD];
    __shared__ float rA[4], rB[4], rC[4];
    for (int j = tid; j < HD; j += 256) hrow[j] = h[(size_t)node * HD + j];
    __syncthreads();
    const float* W1d = W1 + (size_t)d * HD * HD;
    float v[3] = { 0.f, 0.f, 0.f };
    for (int dd = 0; dd < HD; dd++) {
        float hv = hrow[dd];
        const float* wrow = W1d + (size_t)dd * HD;
#pragma unroll
        for (int r = 0; r < 3; r++) v[r] += hv * wrow[r * 256 + tid];
    }
    float s1 = 0.f, s2 = 0.f;
#pragma unroll
    for (int r = 0; r < 3; r++) {
        v[r] += b1[d * HD + r * 256 + tid];
        s1 += v[r]; s2 += v[r] * v[r];
    }
#pragma unroll
    for (int mm = 1; mm < 64; mm <<= 1) { s1 += __shfl_xor(s1, mm); s2 += __shfl_xor(s2, mm); }
    int wave = tid >> 6, lane = tid & 63;
    if (lane == 0) { rA[wave] = s1; rB[wave] = s2; }
    __syncthreads();
    float S1 = rA[0] + rA[1] + rA[2] + rA[3];
    float S2 = rB[0] + rB[1] + rB[2] + rB[3];
    float mean = S1 * (1.f / HD);
    float var = S2 * (1.f / HD) - mean * mean;
    float rstd = rsqrtf(var + 1e-5f);
#pragma unroll
    for (int r = 0; r < 3; r++) {
        int c = r * 256 + tid;
        float zn = (v[r] - mean) * rstd * g[d * HD + c] + be[d * HD + c];
        zz[c] = gelu_f(zn);
    }
    __syncthreads();
    const float* W2d = W2 + (size_t)d * HD * HD;
    const float* orig = (d == 0 ? ft : fi) + (size_t)node * HD;
    float rec[3] = { 0.f, 0.f, 0.f };
    for (int dd = 0; dd < HD; dd++) {
        float zv = zz[dd];
        const float* wrow = W2d + (size_t)dd * HD;
#pragma unroll
        for (int r = 0; r < 3; r++) rec[r] += zv * wrow[r * 256 + tid];
    }
    float pro = 0.f, prr = 0.f, poo = 0.f;
#pragma unroll
    for (int r = 0; r < 3; r++) {
        int c = r * 256 + tid;
        float rv = rec[r] + b2[d * HD + c];
        float o = orig[c];
        pro += rv * o; prr += rv * rv; poo += o * o;
    }
#pragma unroll
    for (int mm = 1; mm < 64; mm <<= 1) {
        pro += __shfl_xor(pro, mm); prr += __shfl_xor(prr, mm); poo += __shfl_xor(poo, mm);
    }
    if (lane == 0) { rA[wave] = pro; rB[wave] = prr; rC[wave] = poo; }
    __syncthreads();
    if (tid == 0) {
        float P = rA[0] + rA[1] + rA[2] + rA[3];
        float R = rB[0] + rB[1] + rB[2] + rB[3];
        float O = rC[0] + rC[1] + rC[2] + rC[3];
        float denom = fmaxf(sqrtf(R) * sqrtf(O), 1e-8f);
        float cosv = P / denom;
        float t = 1.f - cosv;
        rec_part[blockIdx.x] = (t * t) * (1.f / (float)NMASK);
    }
}

// ---------------------------------------------------------------- SPD loss
__global__ __launch_bounds__(256) void k_spd(const float* __restrict__ pa,
        const float* __restrict__ pb, const float* __restrict__ b1,
        const float* __restrict__ g, const float* __restrict__ be,
        const float* __restrict__ w2, const float* __restrict__ b2,
        const float* __restrict__ spd, float* __restrict__ partials) {
    __shared__ float pa_s[HD], g_s[HD], be_s[HD], w2_s[HD];
    __shared__ float wsum[4];
    int i = blockIdx.x;
    for (int t = threadIdx.x; t < HD; t += 256) {
        pa_s[t] = pa[(size_t)i * HD + t] + b1[t];
        g_s[t] = g[t]; be_s[t] = be[t]; w2_s[t] = w2[t];
    }
    __syncthreads();
    int wave = threadIdx.x >> 6, lane = threadIdx.x & 63;
    float bacc = 0.f;
    float b2v = b2[0];
    for (int j = blockIdx.y * 4 + wave; j < NN; j += 16) {
        const float* pbj = pb + (size_t)j * HD;
        float z[12];
        float s1 = 0.f, s2 = 0.f;
#pragma unroll
        for (int r = 0; r < 12; r++) {
            int e = r * 64 + lane;
            float v = pa_s[e] + pbj[e];
            z[r] = v; s1 += v; s2 += v * v;
        }
#pragma unroll
        for (int m = 1; m < 64; m <<= 1) { s1 += __shfl_xor(s1, m); s2 += __shfl_xor(s2, m); }
        float mean = s1 * (1.f / HD);
        float var = s2 * (1.f / HD) - mean * mean;
        float rstd = rsqrtf(var + 1e-5f);
        float mrstd = mean * rstd;
        float dot = 0.f;
#pragma unroll
        for (int r = 0; r < 12; r++) {
            int e = r * 64 + lane;
            float u = fmaf(z[r], rstd, -mrstd);
            float zn = fmaf(u, g_s[e], be_s[e]);
            dot += gelu_f(zn) * w2_s[e];
        }
#pragma unroll
        for (int m = 1; m < 64; m <<= 1) dot += __shfl_xor(dot, m);
        if (lane == 0) {
            float d = (dot + b2v) - spd[(size_t)i * NN + j];
            bacc += d * d;
        }
    }
    if (lane == 0) wsum[wave] = bacc;
    __syncthreads();
    if (threadIdx.x == 0) partials[i * 4 + blockIdx.y] = wsum[0] + wsum[1] + wsum[2] + wsum[3];
}

__global__ void k_final(const float* __restrict__ rec_part,
                        const float* __restrict__ spd_part, float* __restrict__ out) {
    if (blockIdx.x == 0 && threadIdx.x == 0) {
        float rec = 0.f;
        for (int i = 0; i < 2 * NMASK; i++) rec += rec_part[i];
        float sp = 0.f;
        for (int i = 0; i < 4 * NN; i++) sp += spd_part[i];
        out[0] = rec + 0.5f * (sp * (1.f / ((float)NN * (float)NN)));
    }
}

// ================================================================ host
extern "C" void kernel_launch(void* const* d_in, const int* in_sizes, int n_in,
                              void* d_out, int out_size, void* d_ws, size_t ws_size,
                              hipStream_t stream) {
    const float* feat_text = (const float*)d_in[0];
    const float* feat_image = (const float*)d_in[1];
    const float* spd_matrix = (const float*)d_in[2];
    const int*   src       = (const int*)d_in[3];
    const int*   dst       = (const int*)d_in[4];
    const int*   mask_idx  = (const int*)d_in[5];
    const float* mask_token = (const float*)d_in[6];
    const float* gate_W = (const float*)d_in[7];
    const float* gate_b = (const float*)d_in[8];
    const float* exp_W1 = (const float*)d_in[9];
    const float* exp_b1 = (const float*)d_in[10];
    const float* exp_g1 = (const float*)d_in[11];
    const float* exp_be1 = (const float*)d_in[12];
    const float* exp_W2 = (const float*)d_in[13];
    const float* exp_b2 = (const float*)d_in[14];
    const float* gat_W  = (const float*)d_in[15];
    const float* gat_al = (const float*)d_in[16];
    const float* gat_ar = (const float*)d_in[17];
    const float* gat_b  = (const float*)d_in[18];
    const float* dec_W1 = (const float*)d_in[19];
    const float* dec_b1 = (const float*)d_in[20];
    const float* dec_g  = (const float*)d_in[21];
    const float* dec_be = (const float*)d_in[22];
    const float* dec_W2 = (const float*)d_in[23];
    const float* dec_b2 = (const float*)d_in[24];
    const float* spd_W1 = (const float*)d_in[25];
    const float* spd_b1 = (const float*)d_in[26];
    const float* spd_g  = (const float*)d_in[27];
    const float* spd_be = (const float*)d_in[28];
    const float* spd_W2 = (const float*)d_in[29];
    const float* spd_b2 = (const float*)d_in[30];
    (void)in_sizes; (void)n_in; (void)ws_size; (void)out_size;

    float* ws = (float*)d_ws;
    size_t off = 0;
    auto alloc = [&](size_t nfl) { float* p = ws + off; off += (nfl + 3) & ~(size_t)3; return p; };
    float* xm   = alloc((size_t)NN * HD);
    float* hA   = alloc((size_t)NN * HD);
    float* hB   = alloc((size_t)NN * HD);
    float* t1   = alloc((size_t)NN * TOPK * HD);
    float* eo   = alloc((size_t)NN * TOPK * HD);
    float* fbuf = alloc((size_t)NN * NHEADS * HD);
    float* el   = alloc(NN * NHEADS);
    float* er   = alloc(NN * NHEADS);
    float* pab  = alloc((size_t)2 * NN * HD);
    float* topw = alloc(NN * TOPK);
    float* rec_part = alloc(2 * NMASK + 4);
    float* spd_part = alloc(4 * NN);
    int* topi    = (int*)alloc(NN * TOPK);
    int* ecnt    = (int*)alloc(16);
    int* estart  = (int*)alloc(16);
    int* posArr  = (int*)alloc(NN * TOPK);
    int* eofpos  = (int*)alloc(NN * TOPK);
    int* rowlist = (int*)alloc(NN * TOPK);
    int* dcount  = (int*)alloc(NN);
    int* nstart  = (int*)alloc(NN + 4);
    int* esorted = (int*)alloc(EE);
    // bf16 buffers (ushort) — sizes in floats = half the ushort count
    ushort* xm_bf  = (ushort*)alloc((size_t)NN * HD / 2);
    ushort* eh_bf  = (ushort*)alloc((size_t)NN * TOPK * HD / 2);
    ushort* hA_bf  = (ushort*)alloc((size_t)NN * HD / 2);
    ushort* hB_bf  = (ushort*)alloc((size_t)NN * HD / 2);
    ushort* expW1t = (ushort*)alloc((size_t)NEXPERT * HD * HD / 2);
    ushort* expW2t = (ushort*)alloc((size_t)NEXPERT * HD * HD / 2);
    ushort* gatWt  = (ushort*)alloc((size_t)NLAYER * NHEADS * HD * HD / 2);
    ushort* spdW1t = (ushort*)alloc((size_t)2 * HD * HD / 2);

    hipMemsetAsync(ecnt, 0, 16 * sizeof(int), stream);
    hipMemsetAsync(dcount, 0, NN * sizeof(int), stream);

    // weight transpose+convert (independent of activations)
    k_transpose_bf<<<dim3(HD / 32, HD / 32, NEXPERT), dim3(256), 0, stream>>>(
        exp_W1, expW1t, HD, HD, (long)HD * HD, (long)HD * HD);
    k_transpose_bf<<<dim3(HD / 32, HD / 32, NEXPERT), dim3(256), 0, stream>>>(
        exp_W2, expW2t, HD, HD, (long)HD * HD, (long)HD * HD);
    k_transpose_bf<<<dim3(NHEADS * HD / 32, HD / 32, NLAYER), dim3(256), 0, stream>>>(
        gat_W, gatWt, HD, NHEADS * HD, (long)HD * NHEADS * HD, (long)NHEADS * HD * HD);
    k_transpose_bf<<<dim3(HD / 32, HD / 32, 2), dim3(256), 0, stream>>>(
        spd_W1, spdW1t, HD, HD, (long)HD * HD, (long)HD * HD);

    // xm = 0.5*(ft+fi); mask rows; bf16 copy
    k_xm<<<dim3((NN * HD + 255) / 256), dim3(256), 0, stream>>>(feat_text, feat_image, xm, NN * HD);
    k_mask<<<dim3((NMASK * HD + 255) / 256), dim3(256), 0, stream>>>(mask_idx, mask_token, xm);
    k_tobf<<<dim3((NN * HD / 4 + 255) / 256), dim3(256), 0, stream>>>(xm, xm_bf, NN * HD / 4);

    // gating + expert grouping
    k_gate<<<dim3(NN), dim3(256), 0, stream>>>(xm, gate_W, gate_b, topi, topw);
    k_count_assign<<<dim3(3), dim3(256), 0, stream>>>(topi, ecnt);
    k_scan_experts<<<dim3(1), dim3(64), 0, stream>>>(ecnt, estart);
    k_rank_assign<<<dim3(3), dim3(256), 0, stream>>>(topi, estart, posArr, eofpos, rowlist);

    // edge sort (dst-stable)
    k_count_edges<<<dim3(EE / 256), dim3(256), 0, stream>>>(dst, dcount);
    k_scan_nodes<<<dim3(1), dim3(64), 0, stream>>>(dcount, nstart);
    k_rank_edges<<<dim3(EE / 256), dim3(256), 0, stream>>>(dst, nstart, esorted);

    // experts
    k_mfma_gemm<<<dim3(HD / 64, 12, NEXPERT), dim3(256), 0, stream>>>(
        xm_bf, expW1t, t1, 0, HD, HD, HD, (long)HD * HD, 0, rowlist, ecnt, estart);
    k_ln_gelu<<<dim3(NN * TOPK), dim3(256), 0, stream>>>(t1, eh_bf, exp_b1, exp_g1, exp_be1, eofpos);
    k_mfma_gemm<<<dim3(HD / 64, 12, NEXPERT), dim3(256), 0, stream>>>(
        eh_bf, expW2t, eo, 0, HD, HD, HD, (long)HD * HD, 0, nullptr, ecnt, estart);
    k_combine_moe<<<dim3(NN), dim3(256), 0, stream>>>(eo, exp_b2, topi, topw, posArr, hA, hA_bf);

    // GAT layers
    float* hcur = hA; float* hnxt = hB;
    ushort* hcur_bf = hA_bf; ushort* hnxt_bf = hB_bf;
    for (int l = 0; l < NLAYER; l++) {
        k_mfma_gemm<<<dim3(NHEADS * HD / 64, NN / 64, 1), dim3(256), 0, stream>>>(
            hcur_bf, gatWt + (size_t)l * NHEADS * HD * HD, fbuf,
            NN, HD, HD, NHEADS * HD, 0, 0, nullptr, nullptr, nullptr);
        k_el_er<<<dim3(NN), dim3(256), 0, stream>>>(
            fbuf, gat_al + (size_t)l * NHEADS * HD, gat_ar + (size_t)l * NHEADS * HD, el, er);
        k_gat_agg<<<dim3(NN), dim3(256), 0, stream>>>(
            fbuf, el, er, src, esorted, nstart, gat_b + (size_t)l * NHEADS * HD, hnxt, hnxt_bf);
        float* t = hcur; hcur = hnxt; hnxt = t;
        ushort* tb = hcur_bf; hcur_bf = hnxt_bf; hnxt_bf = tb;
    }

    // decoder recon loss
    k_dec<<<dim3(2 * NMASK), dim3(256), 0, stream>>>(
        hcur, mask_idx, dec_W1, dec_b1, dec_g, dec_be, dec_W2, dec_b2,
        feat_text, feat_image, rec_part);

    // SPD projections (pa = z0, pb = z1) + loss
    k_mfma_gemm<<<dim3(HD / 64, NN / 64, 2), dim3(256), 0, stream>>>(
        hcur_bf, spdW1t, pab, NN, HD, HD, HD, (long)HD * HD, (long)NN * HD,
        nullptr, nullptr, nullptr);
    k_spd<<<dim3(NN, 4), dim3(256), 0, stream>>>(
        pab, pab + (size_t)NN * HD, spd_b1, spd_g, spd_be, spd_W2, spd_b2,
        spd_matrix, spd_part);

    // finalize
    k_final<<<dim3(1), dim3(64), 0, stream>>>(rec_part, spd_part, (float*)d_out);
    k_copy_h<<<dim3((NN * HD + 255) / 256), dim3(256), 0, stream>>>(hcur, (float*)d_out);
}

// Round 3
// 406.552 us; speedup vs baseline: 2.2688x; 1.4060x over previous
//
#include <hip/hip_runtime.h>
#include <hip/hip_bf16.h>
#include <math.h>

#define NN 384
#define HD 768
#define EE 12288
#define NCHUNK (EE / 256)
#define NEXPERT 8
#define TOPK 2
#define NLAYER 3
#define NHEADS 4
#define NMASK 38

typedef __attribute__((ext_vector_type(8))) short short8v;
typedef __attribute__((ext_vector_type(4))) float f32x4;
typedef __attribute__((ext_vector_type(4))) int int4v;

__device__ __forceinline__ float gelu_f(float x) {
    return x * 0.5f * (1.f + erff(x * 0.70710678118654752440f));
}

__device__ __forceinline__ ushort f2bf(float x) {
    unsigned u = __float_as_uint(x);
    u += 0x7fffu + ((u >> 16) & 1u);
    return (ushort)(u >> 16);
}

// ---------------------------------------------------------------- elementwise
__global__ void k_xm(const float* __restrict__ a, const float* __restrict__ b,
                     float* __restrict__ xm, int n) {
    int i = blockIdx.x * 256 + threadIdx.x;
    if (i < n) xm[i] = 0.5f * (a[i] + b[i]);
}

__global__ void k_mask(const int* __restrict__ mask_idx, const float* __restrict__ mt,
                       float* __restrict__ xm) {
    int i = blockIdx.x * 256 + threadIdx.x;
    if (i >= NMASK * HD) return;
    int m = i / HD, j = i % HD;
    xm[(size_t)mask_idx[m] * HD + j] = mt[j];
}

__global__ void k_tobf(const float* __restrict__ in, ushort* __restrict__ out, int n4) {
    int i = blockIdx.x * 256 + threadIdx.x;
    if (i >= n4) return;
    float4 v = *reinterpret_cast<const float4*>(in + (size_t)i * 4);
    ushort r0 = f2bf(v.x), r1 = f2bf(v.y), r2 = f2bf(v.z), r3 = f2bf(v.w);
    uint2 p;
    p.x = (unsigned)r0 | ((unsigned)r1 << 16);
    p.y = (unsigned)r2 | ((unsigned)r3 << 16);
    *reinterpret_cast<uint2*>(out + (size_t)i * 4) = p;
}

__global__ void k_copy_h(const float* __restrict__ h, float* __restrict__ out) {
    int i = blockIdx.x * 256 + threadIdx.x;
    if (i < NN * HD) out[1 + i] = h[i];
}

// ---------------------------------------------------------------- transpose+convert weights
// in: f32 [z][K][N] -> out: bf16 [z][N][K]
__global__ __launch_bounds__(256) void k_transpose_bf(
        const float* __restrict__ in, ushort* __restrict__ out,
        int K, int N, long inStrideZ, long outStrideZ) {
    __shared__ float t[32][36];
    int z = blockIdx.z;
    const float* inz = in + (size_t)z * inStrideZ;
    ushort* outz = out + (size_t)z * outStrideZ;
    int n0 = blockIdx.x * 32, k0 = blockIdx.y * 32;
    int r = threadIdx.x >> 3, c4 = (threadIdx.x & 7) * 4;
    float4 v = *reinterpret_cast<const float4*>(inz + (size_t)(k0 + r) * N + n0 + c4);
    t[r][c4] = v.x; t[r][c4 + 1] = v.y; t[r][c4 + 2] = v.z; t[r][c4 + 3] = v.w;
    __syncthreads();
    int orow = n0 + r;
    uint2 p;
    ushort w0 = f2bf(t[c4 + 0][r]);
    ushort w1 = f2bf(t[c4 + 1][r]);
    ushort w2 = f2bf(t[c4 + 2][r]);
    ushort w3 = f2bf(t[c4 + 3][r]);
    p.x = (unsigned)w0 | ((unsigned)w1 << 16);
    p.y = (unsigned)w2 | ((unsigned)w3 << 16);
    *reinterpret_cast<uint2*>(outz + (size_t)orow * K + k0 + c4) = p;
}

// ---------------------------------------------------------------- gating
__global__ __launch_bounds__(256) void k_gate(const float* __restrict__ xm,
        const float* __restrict__ gW, const float* __restrict__ gb,
        int* __restrict__ topi, float* __restrict__ topw) {
    int n = blockIdx.x;
    int grp = threadIdx.x >> 5;
    int l32 = threadIdx.x & 31;
    float p = 0.f;
    for (int dd = l32; dd < HD; dd += 32) p += xm[(size_t)n * HD + dd] * gW[dd * NEXPERT + grp];
#pragma unroll
    for (int m = 1; m < 32; m <<= 1) p += __shfl_xor(p, m, 32);
    __shared__ float logits[NEXPERT];
    if (l32 == 0) logits[grp] = p + gb[grp];
    __syncthreads();
    if (threadIdx.x == 0) {
        float mx = logits[0];
#pragma unroll
        for (int e = 1; e < NEXPERT; e++) mx = fmaxf(mx, logits[e]);
        float sm[NEXPERT]; float s = 0.f;
#pragma unroll
        for (int e = 0; e < NEXPERT; e++) { sm[e] = expf(logits[e] - mx); s += sm[e]; }
#pragma unroll
        for (int e = 0; e < NEXPERT; e++) sm[e] /= s;
        int i0 = 0; float b0 = sm[0];
#pragma unroll
        for (int e = 1; e < NEXPERT; e++) if (sm[e] > b0) { b0 = sm[e]; i0 = e; }
        int i1 = -1; float b1v = -1.f;
#pragma unroll
        for (int e = 0; e < NEXPERT; e++) if (e != i0 && sm[e] > b1v) { b1v = sm[e]; i1 = e; }
        float ssum = b0 + b1v;
        topi[n * 2] = i0; topi[n * 2 + 1] = i1;
        topw[n * 2] = b0 / ssum; topw[n * 2 + 1] = b1v / ssum;
    }
}

// ---------------------------------------------------------------- expert grouping
__global__ void k_count_assign(const int* __restrict__ topi, int* __restrict__ ecnt) {
    int a = blockIdx.x * 256 + threadIdx.x;
    if (a < NN * TOPK) atomicAdd(&ecnt[topi[a]], 1);
}

__global__ void k_scan_experts(const int* __restrict__ ecnt, int* __restrict__ estart) {
    if (threadIdx.x == 0 && blockIdx.x == 0) {
        int s = 0;
        for (int e = 0; e < NEXPERT; e++) { estart[e] = s; s += ecnt[e]; }
        estart[NEXPERT] = s;
    }
}

__global__ void k_rank_assign(const int* __restrict__ topi, const int* __restrict__ estart,
                              int* __restrict__ posArr, int* __restrict__ eofpos,
                              int* __restrict__ rowlist) {
    int a = blockIdx.x * 256 + threadIdx.x;
    if (a >= NN * TOPK) return;
    int e = topi[a]; int rank = 0;
    for (int a2 = 0; a2 < a; a2++) rank += (topi[a2] == e) ? 1 : 0;
    int p = estart[e] + rank;
    posArr[a] = p; eofpos[p] = e; rowlist[p] = a >> 1;
}

// ---------------------------------------------------------------- edge counting sort (by dst, stable, deterministic)
__global__ __launch_bounds__(256) void k_hist(const int* __restrict__ dst,
                                              int* __restrict__ counts) {
    __shared__ int h[NN];
    int c = blockIdx.x;
    for (int i = threadIdx.x; i < NN; i += 256) h[i] = 0;
    __syncthreads();
    atomicAdd(&h[dst[c * 256 + threadIdx.x]], 1);
    __syncthreads();
    for (int i = threadIdx.x; i < NN; i += 256) counts[c * NN + i] = h[i];
}

__global__ __launch_bounds__(NN) void k_scan_all(const int* __restrict__ counts,
        int* __restrict__ chunkbase, int* __restrict__ nstart) {
    __shared__ int tot[NN];
    int n = threadIdx.x;
    int s = 0;
    for (int c = 0; c < NCHUNK; c++) { chunkbase[c * NN + n] = s; s += counts[c * NN + n]; }
    tot[n] = s;
    __syncthreads();
    for (int off = 1; off < NN; off <<= 1) {
        int v = tot[n];
        int add = (n >= off) ? tot[n - off] : 0;
        __syncthreads();
        tot[n] = v + add;
        __syncthreads();
    }
    nstart[n + 1] = tot[n];
    if (n == 0) nstart[0] = 0;
}

__global__ __launch_bounds__(256) void k_rank2(const int* __restrict__ dst,
        const int* __restrict__ chunkbase, const int* __restrict__ nstart,
        int* __restrict__ esorted) {
    __shared__ int ds[256];
    int c = blockIdx.x;
    int e = c * 256 + threadIdx.x;
    int d = dst[e];
    ds[threadIdx.x] = d;
    __syncthreads();
    int r = 0;
    for (int i = 0; i < threadIdx.x; i++) r += (ds[i] == d) ? 1 : 0;
    esorted[nstart[d] + chunkbase[c * NN + d] + r] = e;
}

// ---------------------------------------------------------------- bf16 MFMA GEMM
__device__ __forceinline__ short8v ldfrag(const ushort* s, int r, int kb) {
    int c = kb ^ (r & 7);
    return *reinterpret_cast<const short8v*>(s + r * 64 + c * 8);
}

__global__ __launch_bounds__(256) void k_mfma_gemm(
        const ushort* __restrict__ A, const ushort* __restrict__ Bt, float* __restrict__ C,
        int M, int K, int lda, int ldc, long strideBt, long strideC,
        const int* __restrict__ rowsA, const int* __restrict__ Ms,
        const int* __restrict__ rowStarts) {
    int z = blockIdx.z;
    int Meff = Ms ? Ms[z] : M;
    int row0 = blockIdx.y * 64;
    if (row0 >= Meff) return;
    int col0 = blockIdx.x * 64;
    int rowbase = rowStarts ? rowStarts[z] : 0;
    const ushort* Btz = Bt + (size_t)z * strideBt;
    float* Cz = C + (size_t)rowbase * ldc + (size_t)z * strideC;
    const int* rz = rowsA ? (rowsA + rowbase) : nullptr;

    __shared__ ushort Asm[64 * 64];
    __shared__ ushort Bsm[64 * 64];

    int tid = threadIdx.x;
    int w = tid >> 6, lane = tid & 63;
    int wr = w >> 1, wc = w & 1;
    int l15 = lane & 15, lq = lane >> 4;

    f32x4 acc[2][2];
#pragma unroll
    for (int i = 0; i < 2; i++)
#pragma unroll
        for (int j = 0; j < 2; j++) acc[i][j] = (f32x4){0.f, 0.f, 0.f, 0.f};

    for (int k0 = 0; k0 < K; k0 += 64) {
#pragma unroll
        for (int ii = 0; ii < 2; ii++) {
            int i = tid + ii * 256;
            int r = i >> 3, c = i & 7;
            int cs = c ^ (r & 7);
            int4v av = (int4v){0, 0, 0, 0};
            int grow = row0 + r;
            if (grow < Meff) {
                int srow = rz ? rz[grow] : (rowbase + grow);
                av = *reinterpret_cast<const int4v*>(A + (size_t)srow * lda + k0 + c * 8);
            }
            *reinterpret_cast<int4v*>(&Asm[r * 64 + cs * 8]) = av;
            int4v bv = *reinterpret_cast<const int4v*>(Btz + (size_t)(col0 + r) * K + k0 + c * 8);
            *reinterpret_cast<int4v*>(&Bsm[r * 64 + cs * 8]) = bv;
        }
        __syncthreads();
#pragma unroll
        for (int ks = 0; ks < 2; ks++) {
            int kb = ks * 4 + lq;
            short8v a0 = ldfrag(Asm, wr * 32 + l15, kb);
            short8v a1 = ldfrag(Asm, wr * 32 + 16 + l15, kb);
            short8v b0 = ldfrag(Bsm, wc * 32 + l15, kb);
            short8v b1 = ldfrag(Bsm, wc * 32 + 16 + l15, kb);
            acc[0][0] = __builtin_amdgcn_mfma_f32_16x16x32_bf16(a0, b0, acc[0][0], 0, 0, 0);
            acc[0][1] = __builtin_amdgcn_mfma_f32_16x16x32_bf16(a0, b1, acc[0][1], 0, 0, 0);
            acc[1][0] = __builtin_amdgcn_mfma_f32_16x16x32_bf16(a1, b0, acc[1][0], 0, 0, 0);
            acc[1][1] = __builtin_amdgcn_mfma_f32_16x16x32_bf16(a1, b1, acc[1][1], 0, 0, 0);
        }
        __syncthreads();
    }
#pragma unroll
    for (int ai = 0; ai < 2; ai++)
#pragma unroll
        for (int bi = 0; bi < 2; bi++) {
            int rbase = row0 + wr * 32 + ai * 16 + (lq << 2);
            int cc = col0 + wc * 32 + bi * 16 + l15;
#pragma unroll
            for (int r = 0; r < 4; r++) {
                int rr = rbase + r;
                if (rr < Meff) Cz[(size_t)rr * ldc + cc] = acc[ai][bi][r];
            }
        }
}

// ---------------------------------------------------------------- expert LN+GELU -> bf16
__global__ __launch_bounds__(256) void k_ln_gelu(const float* __restrict__ t1,
        ushort* __restrict__ ehb, const float* __restrict__ b1, const float* __restrict__ g,
        const float* __restrict__ be, const int* __restrict__ eofpos) {
    int row = blockIdx.x;
    int e = eofpos[row];
    int tid = threadIdx.x;
    __shared__ float rA[4], rB[4];
    float v[3]; float s1 = 0.f, s2 = 0.f;
#pragma unroll
    for (int r = 0; r < 3; r++) {
        int c = r * 256 + tid;
        float x = t1[(size_t)row * HD + c] + b1[e * HD + c];
        v[r] = x; s1 += x; s2 += x * x;
    }
#pragma unroll
    for (int m = 1; m < 64; m <<= 1) { s1 += __shfl_xor(s1, m); s2 += __shfl_xor(s2, m); }
    int wave = tid >> 6, lane = tid & 63;
    if (lane == 0) { rA[wave] = s1; rB[wave] = s2; }
    __syncthreads();
    float S1 = rA[0] + rA[1] + rA[2] + rA[3];
    float S2 = rB[0] + rB[1] + rB[2] + rB[3];
    float mean = S1 * (1.f / HD);
    float var = S2 * (1.f / HD) - mean * mean;
    float rstd = rsqrtf(var + 1e-5f);
#pragma unroll
    for (int r = 0; r < 3; r++) {
        int c = r * 256 + tid;
        float zn = (v[r] - mean) * rstd * g[e * HD + c] + be[e * HD + c];
        ehb[(size_t)row * HD + c] = f2bf(gelu_f(zn));
    }
}

__global__ void k_combine_moe(const float* __restrict__ eo, const float* __restrict__ b2,
        const int* __restrict__ topi, const float* __restrict__ topw,
        const int* __restrict__ posArr, float* __restrict__ h, ushort* __restrict__ hb) {
    int n = blockIdx.x;
    int tid = threadIdx.x;
    int e0 = topi[n * 2], e1 = topi[n * 2 + 1];
    float w0 = topw[n * 2], w1 = topw[n * 2 + 1];
    int p0 = posArr[n * 2], p1 = posArr[n * 2 + 1];
    for (int j = tid; j < HD; j += 256) {
        float v0 = eo[(size_t)p0 * HD + j] + b2[e0 * HD + j];
        float v1 = eo[(size_t)p1 * HD + j] + b2[e1 * HD + j];
        float hv = w0 * v0 + w1 * v1;
        h[(size_t)n * HD + j] = hv;
        hb[(size_t)n * HD + j] = f2bf(hv);
    }
}

// ---------------------------------------------------------------- GAT
__global__ __launch_bounds__(256) void k_el_er(const float* __restrict__ f,
        const float* __restrict__ al, const float* __restrict__ ar,
        float* __restrict__ el, float* __restrict__ er) {
    int n = blockIdx.x;
    int hd = threadIdx.x >> 6, lane = threadIdx.x & 63;
    const float* fr = f + ((size_t)n * NHEADS + hd) * HD;
    float pl = 0.f, pr = 0.f;
    for (int j = lane; j < HD; j += 64) {
        float fv = fr[j];
        pl += fv * al[hd * HD + j];
        pr += fv * ar[hd * HD + j];
    }
#pragma unroll
    for (int m = 1; m < 64; m <<= 1) { pl += __shfl_xor(pl, m); pr += __shfl_xor(pr, m); }
    if (lane == 0) { el[n * NHEADS + hd] = pl; er[n * NHEADS + hd] = pr; }
}

__global__ __launch_bounds__(256) void k_gat_agg(const float* __restrict__ f,
        const float* __restrict__ el, const float* __restrict__ er,
        const int* __restrict__ src, const int* __restrict__ esorted,
        const int* __restrict__ nstart, const float* __restrict__ gb,
        float* __restrict__ hout, ushort* __restrict__ hb) {
    int n = blockIdx.x;
    int s0 = nstart[n], cnt = nstart[n + 1] - s0;
    int tid = threadIdx.x;
    __shared__ float red[4][NHEADS];
    __shared__ float emax_s[NHEADS], den_s[NHEADS];
    __shared__ float alpha_s[256][NHEADS];
    __shared__ int sn_s[256];
    float ern[NHEADS];
#pragma unroll
    for (int hd = 0; hd < NHEADS; hd++) ern[hd] = er[n * NHEADS + hd];
    int wave = tid >> 6, lane = tid & 63;

    float mx[NHEADS] = { -1e30f, -1e30f, -1e30f, -1e30f };
    for (int t = tid; t < cnt; t += 256) {
        int e = esorted[s0 + t]; int sn = src[e];
#pragma unroll
        for (int hd = 0; hd < NHEADS; hd++) {
            float v = el[sn * NHEADS + hd] + ern[hd];
            v = (v >= 0.f) ? v : 0.2f * v;
            mx[hd] = fmaxf(mx[hd], v);
        }
    }
#pragma unroll
    for (int hd = 0; hd < NHEADS; hd++) {
#pragma unroll
        for (int m = 1; m < 64; m <<= 1) mx[hd] = fmaxf(mx[hd], __shfl_xor(mx[hd], m));
    }
    if (lane == 0) { for (int hd = 0; hd < NHEADS; hd++) red[wave][hd] = mx[hd]; }
    __syncthreads();
    if (tid == 0) {
#pragma unroll
        for (int hd = 0; hd < NHEADS; hd++)
            emax_s[hd] = fmaxf(fmaxf(red[0][hd], red[1][hd]), fmaxf(red[2][hd], red[3][hd]));
    }
    __syncthreads();
    float sm[NHEADS] = { 0.f, 0.f, 0.f, 0.f };
    for (int t = tid; t < cnt; t += 256) {
        int e = esorted[s0 + t]; int sn = src[e];
#pragma unroll
        for (int hd = 0; hd < NHEADS; hd++) {
            float v = el[sn * NHEADS + hd] + ern[hd];
            v = (v >= 0.f) ? v : 0.2f * v;
            sm[hd] += expf(v - emax_s[hd]);
        }
    }
#pragma unroll
    for (int hd = 0; hd < NHEADS; hd++) {
#pragma unroll
        for (int m = 1; m < 64; m <<= 1) sm[hd] += __shfl_xor(sm[hd], m);
    }
    __syncthreads();
    if (lane == 0) { for (int hd = 0; hd < NHEADS; hd++) red[wave][hd] = sm[hd]; }
    __syncthreads();
    if (tid == 0) {
#pragma unroll
        for (int hd = 0; hd < NHEADS; hd++)
            den_s[hd] = red[0][hd] + red[1][hd] + red[2][hd] + red[3][hd];
    }
    __syncthreads();
    float acc[NHEADS][3] = {};
    for (int c0 = 0; c0 < cnt; c0 += 256) {
        int t = c0 + tid;
        if (t < cnt) {
            int e = esorted[s0 + t]; int sn = src[e];
            sn_s[tid] = sn;
#pragma unroll
            for (int hd = 0; hd < NHEADS; hd++) {
                float v = el[sn * NHEADS + hd] + ern[hd];
                v = (v >= 0.f) ? v : 0.2f * v;
                alpha_s[tid][hd] = expf(v - emax_s[hd]) / fmaxf(den_s[hd], 1e-9f);
            }
        }
        __syncthreads();
        int cm = cnt - c0; if (cm > 256) cm = 256;
        for (int i = 0; i < cm; i++) {
            int sn = sn_s[i];
            const float* fr = f + (size_t)sn * (NHEADS * HD);
#pragma unroll
            for (int hd = 0; hd < NHEADS; hd++) {
                float a = alpha_s[i][hd];
#pragma unroll
                for (int r = 0; r < 3; r++) acc[hd][r] += a * fr[hd * HD + r * 256 + tid];
            }
        }
        __syncthreads();
    }
#pragma unroll
    for (int r = 0; r < 3; r++) {
        int j = r * 256 + tid;
        float s = 0.f;
#pragma unroll
        for (int hd = 0; hd < NHEADS; hd++) s += acc[hd][r] + gb[hd * HD + j];
        float hv = 0.25f * s;
        hout[(size_t)n * HD + j] = hv;
        hb[(size_t)n * HD + j] = f2bf(hv);
    }
}

// ---------------------------------------------------------------- decoder (GEMM-based)
__global__ void k_gather_hm(const float* __restrict__ h, const int* __restrict__ mask_idx,
                            ushort* __restrict__ hm_bf) {
    int m = blockIdx.x;
    int node = mask_idx[m];
    for (int j = threadIdx.x; j < HD; j += 256)
        hm_bf[(size_t)m * HD + j] = f2bf(h[(size_t)node * HD + j]);
}

__global__ __launch_bounds__(256) void k_ln_gelu_dec(const float* __restrict__ t1,
        ushort* __restrict__ zzb, const float* __restrict__ b1, const float* __restrict__ g,
        const float* __restrict__ be) {
    int m = blockIdx.x, d = blockIdx.y;
    int row = d * NMASK + m;
    int tid = threadIdx.x;
    __shared__ float rA[4], rB[4];
    float v[3]; float s1 = 0.f, s2 = 0.f;
#pragma unroll
    for (int r = 0; r < 3; r++) {
        int c = r * 256 + tid;
        float x = t1[(size_t)row * HD + c] + b1[d * HD + c];
        v[r] = x; s1 += x; s2 += x * x;
    }
#pragma unroll
    for (int mm = 1; mm < 64; mm <<= 1) { s1 += __shfl_xor(s1, mm); s2 += __shfl_xor(s2, mm); }
    int wave = tid >> 6, lane = tid & 63;
    if (lane == 0) { rA[wave] = s1; rB[wave] = s2; }
    __syncthreads();
    float S1 = rA[0] + rA[1] + rA[2] + rA[3];
    float S2 = rB[0] + rB[1] + rB[2] + rB[3];
    float mean = S1 * (1.f / HD);
    float var = S2 * (1.f / HD) - mean * mean;
    float rstd = rsqrtf(var + 1e-5f);
#pragma unroll
    for (int r = 0; r < 3; r++) {
        int c = r * 256 + tid;
        float zn = (v[r] - mean) * rstd * g[d * HD + c] + be[d * HD + c];
        zzb[(size_t)row * HD + c] = f2bf(gelu_f(zn));
    }
}

__global__ __launch_bounds__(256) void k_cos(const float* __restrict__ rec,
        const float* __restrict__ b2, const int* __restrict__ mask_idx,
        const float* __restrict__ ft, const float* __restrict__ fi,
        float* __restrict__ rec_part) {
    int b = blockIdx.x;
    int d = b / NMASK, m = b % NMASK;
    int node = mask_idx[m];
    int tid = threadIdx.x;
    __shared__ float rA[4], rB[4], rC[4];
    const float* rrow = rec + (size_t)b * HD;
    const float* orig = (d == 0 ? ft : fi) + (size_t)node * HD;
    float pro = 0.f, prr = 0.f, poo = 0.f;
#pragma unroll
    for (int r = 0; r < 3; r++) {
        int c = r * 256 + tid;
        float rv = rrow[c] + b2[d * HD + c];
        float o = orig[c];
        pro += rv * o; prr += rv * rv; poo += o * o;
    }
#pragma unroll
    for (int mm = 1; mm < 64; mm <<= 1) {
        pro += __shfl_xor(pro, mm); prr += __shfl_xor(prr, mm); poo += __shfl_xor(poo, mm);
    }
    int wave = tid >> 6, lane = tid & 63;
    if (lane == 0) { rA[wave] = pro; rB[wave] = prr; rC[wave] = poo; }
    __syncthreads();
    if (tid == 0) {
        float P = rA[0] + rA[1] + rA[2] + rA[3];
        float R = rB[0] + rB[1] + rB[2] + rB[3];
        float O = rC[0] + rC[1] + rC[2] + rC[3];
        float denom = fmaxf(sqrtf(R) * sqrtf(O), 1e-8f);
        float cosv = P / denom;
        float t = 1.f - cosv;
        rec_part[b] = (t * t) * (1.f / (float)NMASK);
    }
}

// ---------------------------------------------------------------- SPD loss
__global__ __launch_bounds__(256) void k_spd(const float* __restrict__ pa,
        const float* __restrict__ pb, const float* __restrict__ b1,
        const float* __restrict__ g, const float* __restrict__ be,
        const float* __restrict__ w2, const float* __restrict__ b2,
        const float* __restrict__ spd, float* __restrict__ partials) {
    __shared__ float pa_s[HD], g_s[HD], be_s[HD], w2_s[HD];
    __shared__ float wsum[4];
    int i = blockIdx.x;
    for (int t = threadIdx.x; t < HD; t += 256) {
        pa_s[t] = pa[(size_t)i * HD + t] + b1[t];
        g_s[t] = g[t]; be_s[t] = be[t]; w2_s[t] = w2[t];
    }
    __syncthreads();
    int wave = threadIdx.x >> 6, lane = threadIdx.x & 63;
    float bacc = 0.f;
    float b2v = b2[0];
    for (int j = blockIdx.y * 4 + wave; j < NN; j += 32) {
        const float* pbj = pb + (size_t)j * HD;
        float z[12];
        float s1 = 0.f, s2 = 0.f;
#pragma unroll
        for (int r = 0; r < 12; r++) {
            int e = r * 64 + lane;
            float v = pa_s[e] + pbj[e];
            z[r] = v; s1 += v; s2 += v * v;
        }
#pragma unroll
        for (int m = 1; m < 64; m <<= 1) { s1 += __shfl_xor(s1, m); s2 += __shfl_xor(s2, m); }
        float mean = s1 * (1.f / HD);
        float var = s2 * (1.f / HD) - mean * mean;
        float rstd = rsqrtf(var + 1e-5f);
        float mrstd = mean * rstd;
        float dot = 0.f;
#pragma unroll
        for (int r = 0; r < 12; r++) {
            int e = r * 64 + lane;
            float u = fmaf(z[r], rstd, -mrstd);
            float zn = fmaf(u, g_s[e], be_s[e]);
            dot += gelu_f(zn) * w2_s[e];
        }
#pragma unroll
        for (int m = 1; m < 64; m <<= 1) dot += __shfl_xor(dot, m);
        if (lane == 0) {
            float d = (dot + b2v) - spd[(size_t)i * NN + j];
            bacc += d * d;
        }
    }
    if (lane == 0) wsum[wave] = bacc;
    __syncthreads();
    if (threadIdx.x == 0) partials[i * 8 + blockIdx.y] = wsum[0] + wsum[1] + wsum[2] + wsum[3];
}

__global__ void k_final(const float* __restrict__ rec_part,
                        const float* __restrict__ spd_part, float* __restrict__ out) {
    if (blockIdx.x == 0 && threadIdx.x == 0) {
        float rec = 0.f;
        for (int i = 0; i < 2 * NMASK; i++) rec += rec_part[i];
        float sp = 0.f;
        for (int i = 0; i < 8 * NN; i++) sp += spd_part[i];
        out[0] = rec + 0.5f * (sp * (1.f / ((float)NN * (float)NN)));
    }
}

// ================================================================ host
extern "C" void kernel_launch(void* const* d_in, const int* in_sizes, int n_in,
                              void* d_out, int out_size, void* d_ws, size_t ws_size,
                              hipStream_t stream) {
    const float* feat_text = (const float*)d_in[0];
    const float* feat_image = (const float*)d_in[1];
    const float* spd_matrix = (const float*)d_in[2];
    const int*   src       = (const int*)d_in[3];
    const int*   dst       = (const int*)d_in[4];
    const int*   mask_idx  = (const int*)d_in[5];
    const float* mask_token = (const float*)d_in[6];
    const float* gate_W = (const float*)d_in[7];
    const float* gate_b = (const float*)d_in[8];
    const float* exp_W1 = (const float*)d_in[9];
    const float* exp_b1 = (const float*)d_in[10];
    const float* exp_g1 = (const float*)d_in[11];
    const float* exp_be1 = (const float*)d_in[12];
    const float* exp_W2 = (const float*)d_in[13];
    const float* exp_b2 = (const float*)d_in[14];
    const float* gat_W  = (const float*)d_in[15];
    const float* gat_al = (const float*)d_in[16];
    const float* gat_ar = (const float*)d_in[17];
    const float* gat_b  = (const float*)d_in[18];
    const float* dec_W1 = (const float*)d_in[19];
    const float* dec_b1 = (const float*)d_in[20];
    const float* dec_g  = (const float*)d_in[21];
    const float* dec_be = (const float*)d_in[22];
    const float* dec_W2 = (const float*)d_in[23];
    const float* dec_b2 = (const float*)d_in[24];
    const float* spd_W1 = (const float*)d_in[25];
    const float* spd_b1 = (const float*)d_in[26];
    const float* spd_g  = (const float*)d_in[27];
    const float* spd_be = (const float*)d_in[28];
    const float* spd_W2 = (const float*)d_in[29];
    const float* spd_b2 = (const float*)d_in[30];
    (void)in_sizes; (void)n_in; (void)ws_size; (void)out_size;

    float* ws = (float*)d_ws;
    size_t off = 0;
    auto alloc = [&](size_t nfl) { float* p = ws + off; off += (nfl + 3) & ~(size_t)3; return p; };
    float* xm   = alloc((size_t)NN * HD);
    float* hA   = alloc((size_t)NN * HD);
    float* hB   = alloc((size_t)NN * HD);
    float* t1   = alloc((size_t)NN * TOPK * HD);     // also decoder t_dec (2*38*768 fits)
    float* eo   = alloc((size_t)NN * TOPK * HD);     // also decoder rec buffer
    float* fbuf = alloc((size_t)NN * NHEADS * HD);
    float* el   = alloc(NN * NHEADS);
    float* er   = alloc(NN * NHEADS);
    float* pab  = alloc((size_t)2 * NN * HD);
    float* topw = alloc(NN * TOPK);
    float* rec_part = alloc(2 * NMASK + 4);
    float* spd_part = alloc(8 * NN);
    int* topi    = (int*)alloc(NN * TOPK);
    int* ecnt    = (int*)alloc(16);
    int* estart  = (int*)alloc(16);
    int* posArr  = (int*)alloc(NN * TOPK);
    int* eofpos  = (int*)alloc(NN * TOPK);
    int* rowlist = (int*)alloc(NN * TOPK);
    int* nstart  = (int*)alloc(NN + 4);
    int* esorted = (int*)alloc(EE);
    int* counts    = (int*)alloc((size_t)NCHUNK * NN);
    int* chunkbase = (int*)alloc((size_t)NCHUNK * NN);
    // bf16 buffers (ushort) — sizes in floats = half the ushort count
    ushort* xm_bf  = (ushort*)alloc((size_t)NN * HD / 2);
    ushort* eh_bf  = (ushort*)alloc((size_t)NN * TOPK * HD / 2);  // also decoder zz_bf
    ushort* hA_bf  = (ushort*)alloc((size_t)NN * HD / 2);
    ushort* hB_bf  = (ushort*)alloc((size_t)NN * HD / 2);
    ushort* hm_bf  = (ushort*)alloc((size_t)NMASK * HD / 2 + 4);
    ushort* expW1t = (ushort*)alloc((size_t)NEXPERT * HD * HD / 2);
    ushort* expW2t = (ushort*)alloc((size_t)NEXPERT * HD * HD / 2);
    ushort* gatWt  = (ushort*)alloc((size_t)NLAYER * NHEADS * HD * HD / 2);
    ushort* spdW1t = (ushort*)alloc((size_t)2 * HD * HD / 2);
    ushort* decW1t = (ushort*)alloc((size_t)2 * HD * HD / 2);
    ushort* decW2t = (ushort*)alloc((size_t)2 * HD * HD / 2);

    hipMemsetAsync(ecnt, 0, 16 * sizeof(int), stream);

    // weight transpose+convert (independent of activations)
    k_transpose_bf<<<dim3(HD / 32, HD / 32, NEXPERT), dim3(256), 0, stream>>>(
        exp_W1, expW1t, HD, HD, (long)HD * HD, (long)HD * HD);
    k_transpose_bf<<<dim3(HD / 32, HD / 32, NEXPERT), dim3(256), 0, stream>>>(
        exp_W2, expW2t, HD, HD, (long)HD * HD, (long)HD * HD);
    k_transpose_bf<<<dim3(NHEADS * HD / 32, HD / 32, NLAYER), dim3(256), 0, stream>>>(
        gat_W, gatWt, HD, NHEADS * HD, (long)HD * NHEADS * HD, (long)NHEADS * HD * HD);
    k_transpose_bf<<<dim3(HD / 32, HD / 32, 2), dim3(256), 0, stream>>>(
        spd_W1, spdW1t, HD, HD, (long)HD * HD, (long)HD * HD);
    k_transpose_bf<<<dim3(HD / 32, HD / 32, 2), dim3(256), 0, stream>>>(
        dec_W1, decW1t, HD, HD, (long)HD * HD, (long)HD * HD);
    k_transpose_bf<<<dim3(HD / 32, HD / 32, 2), dim3(256), 0, stream>>>(
        dec_W2, decW2t, HD, HD, (long)HD * HD, (long)HD * HD);

    // xm = 0.5*(ft+fi); mask rows; bf16 copy
    k_xm<<<dim3((NN * HD + 255) / 256), dim3(256), 0, stream>>>(feat_text, feat_image, xm, NN * HD);
    k_mask<<<dim3((NMASK * HD + 255) / 256), dim3(256), 0, stream>>>(mask_idx, mask_token, xm);
    k_tobf<<<dim3((NN * HD / 4 + 255) / 256), dim3(256), 0, stream>>>(xm, xm_bf, NN * HD / 4);

    // gating + expert grouping
    k_gate<<<dim3(NN), dim3(256), 0, stream>>>(xm, gate_W, gate_b, topi, topw);
    k_count_assign<<<dim3(3), dim3(256), 0, stream>>>(topi, ecnt);
    k_scan_experts<<<dim3(1), dim3(64), 0, stream>>>(ecnt, estart);
    k_rank_assign<<<dim3(3), dim3(256), 0, stream>>>(topi, estart, posArr, eofpos, rowlist);

    // edge counting sort (dst-stable, deterministic)
    k_hist<<<dim3(NCHUNK), dim3(256), 0, stream>>>(dst, counts);
    k_scan_all<<<dim3(1), dim3(NN), 0, stream>>>(counts, chunkbase, nstart);
    k_rank2<<<dim3(NCHUNK), dim3(256), 0, stream>>>(dst, chunkbase, nstart, esorted);

    // experts
    k_mfma_gemm<<<dim3(HD / 64, 12, NEXPERT), dim3(256), 0, stream>>>(
        xm_bf, expW1t, t1, 0, HD, HD, HD, (long)HD * HD, 0, rowlist, ecnt, estart);
    k_ln_gelu<<<dim3(NN * TOPK), dim3(256), 0, stream>>>(t1, eh_bf, exp_b1, exp_g1, exp_be1, eofpos);
    k_mfma_gemm<<<dim3(HD / 64, 12, NEXPERT), dim3(256), 0, stream>>>(
        eh_bf, expW2t, eo, 0, HD, HD, HD, (long)HD * HD, 0, nullptr, ecnt, estart);
    k_combine_moe<<<dim3(NN), dim3(256), 0, stream>>>(eo, exp_b2, topi, topw, posArr, hA, hA_bf);

    // GAT layers
    float* hcur = hA; float* hnxt = hB;
    ushort* hcur_bf = hA_bf; ushort* hnxt_bf = hB_bf;
    for (int l = 0; l < NLAYER; l++) {
        k_mfma_gemm<<<dim3(NHEADS * HD / 64, NN / 64, 1), dim3(256), 0, stream>>>(
            hcur_bf, gatWt + (size_t)l * NHEADS * HD * HD, fbuf,
            NN, HD, HD, NHEADS * HD, 0, 0, nullptr, nullptr, nullptr);
        k_el_er<<<dim3(NN), dim3(256), 0, stream>>>(
            fbuf, gat_al + (size_t)l * NHEADS * HD, gat_ar + (size_t)l * NHEADS * HD, el, er);
        k_gat_agg<<<dim3(NN), dim3(256), 0, stream>>>(
            fbuf, el, er, src, esorted, nstart, gat_b + (size_t)l * NHEADS * HD, hnxt, hnxt_bf);
        float* t = hcur; hcur = hnxt; hnxt = t;
        ushort* tb = hcur_bf; hcur_bf = hnxt_bf; hnxt_bf = tb;
    }

    // decoder recon loss (GEMM-based); reuse t1 as t_dec, eo as rec, eh_bf as zz_bf
    k_gather_hm<<<dim3(NMASK), dim3(256), 0, stream>>>(hcur, mask_idx, hm_bf);
    k_mfma_gemm<<<dim3(HD / 64, 1, 2), dim3(256), 0, stream>>>(
        hm_bf, decW1t, t1, NMASK, HD, HD, HD, (long)HD * HD, (long)NMASK * HD,
        nullptr, nullptr, nullptr);
    k_ln_gelu_dec<<<dim3(NMASK, 2), dim3(256), 0, stream>>>(t1, eh_bf, dec_b1, dec_g, dec_be);
    k_mfma_gemm<<<dim3(HD / 64, 1, 2), dim3(256), 0, stream>>>(
        eh_bf, decW2t, eo, NMASK, HD, HD, HD, (long)HD * HD, (long)NMASK * HD,
        nullptr, nullptr, nullptr);
    k_cos<<<dim3(2 * NMASK), dim3(256), 0, stream>>>(
        eo, dec_b2, mask_idx, feat_text, feat_image, rec_part);

    // SPD projections (pa = z0, pb = z1) + loss
    k_mfma_gemm<<<dim3(HD / 64, NN / 64, 2), dim3(256), 0, stream>>>(
        hcur_bf, spdW1t, pab, NN, HD, HD, HD, (long)HD * HD, (long)NN * HD,
        nullptr, nullptr, nullptr);
    k_spd<<<dim3(NN, 8), dim3(256), 0, stream>>>(
        pab, pab + (size_t)NN * HD, spd_b1, spd_g, spd_be, spd_W2, spd_b2,
        spd_matrix, spd_part);

    // finalize
    k_final<<<dim3(1), dim3(64), 0, stream>>>(rec_part, spd_part, (float*)d_out);
    k_copy_h<<<dim3((NN * HD + 255) / 256), dim3(256), 0, stream>>>(hcur, (float*)d_out);
}

// Round 4
// 369.375 us; speedup vs baseline: 2.4972x; 1.1006x over previous
//
#include <hip/hip_runtime.h>
#include <hip/hip_bf16.h>
#include <math.h>

#define NN 384
#define HD 768
#define EE 12288
#define NCHUNK (EE / 256)
#define NEXPERT 8
#define TOPK 2
#define NLAYER 3
#define NHEADS 4
#define NMASK 38

typedef __attribute__((ext_vector_type(8))) short short8v;
typedef __attribute__((ext_vector_type(4))) float f32x4;
typedef __attribute__((ext_vector_type(4))) int int4v;

__device__ __forceinline__ float gelu_f(float x) {
    return x * 0.5f * (1.f + erff(x * 0.70710678118654752440f));
}

// tanh-approx GELU (SPD path only): x * sigmoid(x*(1.5957691 + 0.07135538*x^2))
__device__ __forceinline__ float gelu_fast(float x) {
    float u = x * fmaf(x * x, 0.07135538f, 1.5957691f);
    float e = __expf(-u);
    return x * __builtin_amdgcn_rcpf(1.f + e);
}

__device__ __forceinline__ ushort f2bf(float x) {
    unsigned u = __float_as_uint(x);
    u += 0x7fffu + ((u >> 16) & 1u);
    return (ushort)(u >> 16);
}

// ---------------------------------------------------------------- fused xm (+mask +bf16)
__global__ __launch_bounds__(256) void k_xm_fused(const float* __restrict__ a,
        const float* __restrict__ b, const int* __restrict__ mask_idx,
        const float* __restrict__ mt, float* __restrict__ xm, ushort* __restrict__ xm_bf) {
    int n = blockIdx.x, tid = threadIdx.x;
    __shared__ int ism;
    if (tid == 0) ism = 0;
    __syncthreads();
    if (tid < NMASK && mask_idx[tid] == n) ism = 1;
    __syncthreads();
#pragma unroll
    for (int r = 0; r < 3; r++) {
        int j = r * 256 + tid;
        float v = ism ? mt[j] : 0.5f * (a[(size_t)n * HD + j] + b[(size_t)n * HD + j]);
        xm[(size_t)n * HD + j] = v;
        xm_bf[(size_t)n * HD + j] = f2bf(v);
    }
}

// ---------------------------------------------------------------- all weight transposes
// f32 [z][K][N] -> bf16 [z][N][K], 32x32 tiles, 6 segments flattened into one grid.
__global__ __launch_bounds__(256) void k_transpose_all(
        const float* __restrict__ w1, const float* __restrict__ w2,
        const float* __restrict__ gw, const float* __restrict__ sw,
        const float* __restrict__ dw1, const float* __restrict__ dw2,
        ushort* __restrict__ o1, ushort* __restrict__ o2, ushort* __restrict__ og,
        ushort* __restrict__ os, ushort* __restrict__ od1, ushort* __restrict__ od2) {
    int b = blockIdx.x;
    const float* src; ushort* dst; int N, loc, tilesX;
    if (b < 4608)       { src = w1;  dst = o1;  N = HD;     loc = b;         tilesX = 24; }
    else if (b < 9216)  { src = w2;  dst = o2;  N = HD;     loc = b - 4608;  tilesX = 24; }
    else if (b < 16128) { src = gw;  dst = og;  N = 4 * HD; loc = b - 9216;  tilesX = 96; }
    else if (b < 17280) { src = sw;  dst = os;  N = HD;     loc = b - 16128; tilesX = 24; }
    else if (b < 18432) { src = dw1; dst = od1; N = HD;     loc = b - 17280; tilesX = 24; }
    else                { src = dw2; dst = od2; N = HD;     loc = b - 18432; tilesX = 24; }
    const int K = HD;
    int tilesPerZ = tilesX * 24;
    int z = loc / tilesPerZ;
    int rem = loc - z * tilesPerZ;
    int ty = rem / tilesX, tx = rem - ty * tilesX;
    const float* inz = src + (size_t)z * K * N;
    ushort* outz = dst + (size_t)z * K * N;
    int n0 = tx * 32, k0 = ty * 32;

    __shared__ float t[32][36];
    int r = threadIdx.x >> 3, c4 = (threadIdx.x & 7) * 4;
    float4 v = *reinterpret_cast<const float4*>(inz + (size_t)(k0 + r) * N + n0 + c4);
    t[r][c4] = v.x; t[r][c4 + 1] = v.y; t[r][c4 + 2] = v.z; t[r][c4 + 3] = v.w;
    __syncthreads();
    int orow = n0 + r;
    uint2 p;
    ushort b0 = f2bf(t[c4 + 0][r]);
    ushort b1 = f2bf(t[c4 + 1][r]);
    ushort b2 = f2bf(t[c4 + 2][r]);
    ushort b3 = f2bf(t[c4 + 3][r]);
    p.x = (unsigned)b0 | ((unsigned)b1 << 16);
    p.y = (unsigned)b2 | ((unsigned)b3 << 16);
    *reinterpret_cast<uint2*>(outz + (size_t)orow * K + k0 + c4) = p;
}

// ---------------------------------------------------------------- gating
__global__ __launch_bounds__(256) void k_gate(const float* __restrict__ xm,
        const float* __restrict__ gW, const float* __restrict__ gb,
        int* __restrict__ topi, float* __restrict__ topw) {
    int n = blockIdx.x;
    int grp = threadIdx.x >> 5;
    int l32 = threadIdx.x & 31;
    float p = 0.f;
    for (int dd = l32; dd < HD; dd += 32) p += xm[(size_t)n * HD + dd] * gW[dd * NEXPERT + grp];
#pragma unroll
    for (int m = 1; m < 32; m <<= 1) p += __shfl_xor(p, m, 32);
    __shared__ float logits[NEXPERT];
    if (l32 == 0) logits[grp] = p + gb[grp];
    __syncthreads();
    if (threadIdx.x == 0) {
        float mx = logits[0];
#pragma unroll
        for (int e = 1; e < NEXPERT; e++) mx = fmaxf(mx, logits[e]);
        float sm[NEXPERT]; float s = 0.f;
#pragma unroll
        for (int e = 0; e < NEXPERT; e++) { sm[e] = expf(logits[e] - mx); s += sm[e]; }
#pragma unroll
        for (int e = 0; e < NEXPERT; e++) sm[e] /= s;
        int i0 = 0; float b0 = sm[0];
#pragma unroll
        for (int e = 1; e < NEXPERT; e++) if (sm[e] > b0) { b0 = sm[e]; i0 = e; }
        int i1 = -1; float b1v = -1.f;
#pragma unroll
        for (int e = 0; e < NEXPERT; e++) if (e != i0 && sm[e] > b1v) { b1v = sm[e]; i1 = e; }
        float ssum = b0 + b1v;
        topi[n * 2] = i0; topi[n * 2 + 1] = i1;
        topw[n * 2] = b0 / ssum; topw[n * 2 + 1] = b1v / ssum;
    }
}

// ---------------------------------------------------------------- MoE meta (single block)
__global__ __launch_bounds__(256) void k_moe_meta(const int* __restrict__ topi,
        int* __restrict__ ecnt, int* __restrict__ estart, int* __restrict__ posArr,
        int* __restrict__ eofpos, int* __restrict__ rowlist, int* __restrict__ dec_rs) {
    __shared__ int ti[NN * TOPK];
    __shared__ int cnt[NEXPERT];
    __shared__ int est[NEXPERT + 1];
    int tid = threadIdx.x;
    if (tid < NEXPERT) cnt[tid] = 0;
    __syncthreads();
    for (int a = tid; a < NN * TOPK; a += 256) ti[a] = topi[a];
    __syncthreads();
    for (int a = tid; a < NN * TOPK; a += 256) atomicAdd(&cnt[ti[a]], 1);
    __syncthreads();
    if (tid == 0) {
        int s = 0;
        for (int e = 0; e < NEXPERT; e++) { est[e] = s; s += cnt[e]; }
        est[NEXPERT] = s;
        dec_rs[0] = 0; dec_rs[1] = NMASK;
    }
    __syncthreads();
    if (tid < NEXPERT) { ecnt[tid] = cnt[tid]; estart[tid] = est[tid]; }
    if (tid == 0) estart[NEXPERT] = est[NEXPERT];
    for (int a = tid; a < NN * TOPK; a += 256) {
        int e = ti[a]; int rank = 0;
        for (int a2 = 0; a2 < a; a2++) rank += (ti[a2] == e) ? 1 : 0;
        int p = est[e] + rank;
        posArr[a] = p; eofpos[p] = e; rowlist[p] = a >> 1;
    }
}

// ---------------------------------------------------------------- edge counting sort
__global__ __launch_bounds__(256) void k_hist(const int* __restrict__ dst,
                                              int* __restrict__ counts) {
    __shared__ int h[NN];
    int c = blockIdx.x;
    for (int i = threadIdx.x; i < NN; i += 256) h[i] = 0;
    __syncthreads();
    atomicAdd(&h[dst[c * 256 + threadIdx.x]], 1);
    __syncthreads();
    for (int i = threadIdx.x; i < NN; i += 256) counts[c * NN + i] = h[i];
}

__global__ __launch_bounds__(NN) void k_scan_all(const int* __restrict__ counts,
        int* __restrict__ chunkbase, int* __restrict__ nstart) {
    __shared__ int tot[NN];
    int n = threadIdx.x;
    int s = 0;
    for (int c = 0; c < NCHUNK; c++) { chunkbase[c * NN + n] = s; s += counts[c * NN + n]; }
    tot[n] = s;
    __syncthreads();
    for (int off = 1; off < NN; off <<= 1) {
        int v = tot[n];
        int add = (n >= off) ? tot[n - off] : 0;
        __syncthreads();
        tot[n] = v + add;
        __syncthreads();
    }
    nstart[n + 1] = tot[n];
    if (n == 0) nstart[0] = 0;
}

__global__ __launch_bounds__(256) void k_rank2(const int* __restrict__ dst,
        const int* __restrict__ chunkbase, const int* __restrict__ nstart,
        int* __restrict__ esorted) {
    __shared__ int ds[256];
    int c = blockIdx.x;
    int e = c * 256 + threadIdx.x;
    int d = dst[e];
    ds[threadIdx.x] = d;
    __syncthreads();
    int r = 0;
    for (int i = 0; i < threadIdx.x; i++) r += (ds[i] == d) ? 1 : 0;
    esorted[nstart[d] + chunkbase[c * NN + d] + r] = e;
}

// ---------------------------------------------------------------- bf16 MFMA GEMM
__device__ __forceinline__ short8v ldfrag(const ushort* s, int r, int kb) {
    int c = kb ^ (r & 7);
    return *reinterpret_cast<const short8v*>(s + r * 64 + c * 8);
}

__global__ __launch_bounds__(256) void k_mfma_gemm(
        const ushort* __restrict__ A, const ushort* __restrict__ Bt, float* __restrict__ C,
        int M, int K, int lda, int ldc, long strideBt, long strideC,
        const int* __restrict__ rowsA, const int* __restrict__ Ms,
        const int* __restrict__ rowStarts) {
    int z = blockIdx.z;
    int Meff = Ms ? Ms[z] : M;
    int row0 = blockIdx.y * 64;
    if (row0 >= Meff) return;
    int col0 = blockIdx.x * 64;
    int rowbase = rowStarts ? rowStarts[z] : 0;
    const ushort* Btz = Bt + (size_t)z * strideBt;
    float* Cz = C + (size_t)rowbase * ldc + (size_t)z * strideC;
    const int* rz = rowsA ? (rowsA + rowbase) : nullptr;

    __shared__ ushort Asm[64 * 64];
    __shared__ ushort Bsm[64 * 64];

    int tid = threadIdx.x;
    int w = tid >> 6, lane = tid & 63;
    int wr = w >> 1, wc = w & 1;
    int l15 = lane & 15, lq = lane >> 4;

    f32x4 acc[2][2];
#pragma unroll
    for (int i = 0; i < 2; i++)
#pragma unroll
        for (int j = 0; j < 2; j++) acc[i][j] = (f32x4){0.f, 0.f, 0.f, 0.f};

    for (int k0 = 0; k0 < K; k0 += 64) {
#pragma unroll
        for (int ii = 0; ii < 2; ii++) {
            int i = tid + ii * 256;
            int r = i >> 3, c = i & 7;
            int cs = c ^ (r & 7);
            int4v av = (int4v){0, 0, 0, 0};
            int grow = row0 + r;
            if (grow < Meff) {
                int srow = rz ? rz[grow] : (rowbase + grow);
                av = *reinterpret_cast<const int4v*>(A + (size_t)srow * lda + k0 + c * 8);
            }
            *reinterpret_cast<int4v*>(&Asm[r * 64 + cs * 8]) = av;
            int4v bv = *reinterpret_cast<const int4v*>(Btz + (size_t)(col0 + r) * K + k0 + c * 8);
            *reinterpret_cast<int4v*>(&Bsm[r * 64 + cs * 8]) = bv;
        }
        __syncthreads();
#pragma unroll
        for (int ks = 0; ks < 2; ks++) {
            int kb = ks * 4 + lq;
            short8v a0 = ldfrag(Asm, wr * 32 + l15, kb);
            short8v a1 = ldfrag(Asm, wr * 32 + 16 + l15, kb);
            short8v b0 = ldfrag(Bsm, wc * 32 + l15, kb);
            short8v b1 = ldfrag(Bsm, wc * 32 + 16 + l15, kb);
            acc[0][0] = __builtin_amdgcn_mfma_f32_16x16x32_bf16(a0, b0, acc[0][0], 0, 0, 0);
            acc[0][1] = __builtin_amdgcn_mfma_f32_16x16x32_bf16(a0, b1, acc[0][1], 0, 0, 0);
            acc[1][0] = __builtin_amdgcn_mfma_f32_16x16x32_bf16(a1, b0, acc[1][0], 0, 0, 0);
            acc[1][1] = __builtin_amdgcn_mfma_f32_16x16x32_bf16(a1, b1, acc[1][1], 0, 0, 0);
        }
        __syncthreads();
    }
#pragma unroll
    for (int ai = 0; ai < 2; ai++)
#pragma unroll
        for (int bi = 0; bi < 2; bi++) {
            int rbase = row0 + wr * 32 + ai * 16 + (lq << 2);
            int cc = col0 + wc * 32 + bi * 16 + l15;
#pragma unroll
            for (int r = 0; r < 4; r++) {
                int rr = rbase + r;
                if (rr < Meff) Cz[(size_t)rr * ldc + cc] = acc[ai][bi][r];
            }
        }
}

// ---------------------------------------------------------------- expert LN+GELU -> bf16
__global__ __launch_bounds__(256) void k_ln_gelu(const float* __restrict__ t1,
        ushort* __restrict__ ehb, const float* __restrict__ b1, const float* __restrict__ g,
        const float* __restrict__ be, const int* __restrict__ eofpos) {
    int row = blockIdx.x;
    int e = eofpos[row];
    int tid = threadIdx.x;
    __shared__ float rA[4], rB[4];
    float v[3]; float s1 = 0.f, s2 = 0.f;
#pragma unroll
    for (int r = 0; r < 3; r++) {
        int c = r * 256 + tid;
        float x = t1[(size_t)row * HD + c] + b1[e * HD + c];
        v[r] = x; s1 += x; s2 += x * x;
    }
#pragma unroll
    for (int m = 1; m < 64; m <<= 1) { s1 += __shfl_xor(s1, m); s2 += __shfl_xor(s2, m); }
    int wave = tid >> 6, lane = tid & 63;
    if (lane == 0) { rA[wave] = s1; rB[wave] = s2; }
    __syncthreads();
    float S1 = rA[0] + rA[1] + rA[2] + rA[3];
    float S2 = rB[0] + rB[1] + rB[2] + rB[3];
    float mean = S1 * (1.f / HD);
    float var = S2 * (1.f / HD) - mean * mean;
    float rstd = rsqrtf(var + 1e-5f);
#pragma unroll
    for (int r = 0; r < 3; r++) {
        int c = r * 256 + tid;
        float zn = (v[r] - mean) * rstd * g[e * HD + c] + be[e * HD + c];
        ehb[(size_t)row * HD + c] = f2bf(gelu_f(zn));
    }
}

__global__ void k_combine_moe(const float* __restrict__ eo, const float* __restrict__ b2,
        const int* __restrict__ topi, const float* __restrict__ topw,
        const int* __restrict__ posArr, float* __restrict__ h, ushort* __restrict__ hb) {
    int n = blockIdx.x;
    int tid = threadIdx.x;
    int e0 = topi[n * 2], e1 = topi[n * 2 + 1];
    float w0 = topw[n * 2], w1 = topw[n * 2 + 1];
    int p0 = posArr[n * 2], p1 = posArr[n * 2 + 1];
    for (int j = tid; j < HD; j += 256) {
        float v0 = eo[(size_t)p0 * HD + j] + b2[e0 * HD + j];
        float v1 = eo[(size_t)p1 * HD + j] + b2[e1 * HD + j];
        float hv = w0 * v0 + w1 * v1;
        h[(size_t)n * HD + j] = hv;
        hb[(size_t)n * HD + j] = f2bf(hv);
    }
}

// ---------------------------------------------------------------- GAT
__global__ __launch_bounds__(256) void k_el_er(const float* __restrict__ f,
        const float* __restrict__ al, const float* __restrict__ ar,
        float* __restrict__ el, float* __restrict__ er) {
    int n = blockIdx.x;
    int hd = threadIdx.x >> 6, lane = threadIdx.x & 63;
    const float* fr = f + ((size_t)n * NHEADS + hd) * HD;
    float pl = 0.f, pr = 0.f;
    for (int j = lane; j < HD; j += 64) {
        float fv = fr[j];
        pl += fv * al[hd * HD + j];
        pr += fv * ar[hd * HD + j];
    }
#pragma unroll
    for (int m = 1; m < 64; m <<= 1) { pl += __shfl_xor(pl, m); pr += __shfl_xor(pr, m); }
    if (lane == 0) { el[n * NHEADS + hd] = pl; er[n * NHEADS + hd] = pr; }
}

__global__ __launch_bounds__(256) void k_gat_agg(const float* __restrict__ f,
        const float* __restrict__ el, const float* __restrict__ er,
        const int* __restrict__ src, const int* __restrict__ esorted,
        const int* __restrict__ nstart, const float* __restrict__ gb,
        float* __restrict__ hout, ushort* __restrict__ hb) {
    int n = blockIdx.x;
    int s0 = nstart[n], cnt = nstart[n + 1] - s0;
    int tid = threadIdx.x;
    __shared__ float red[4][NHEADS];
    __shared__ float emax_s[NHEADS], den_s[NHEADS];
    __shared__ float alpha_s[256][NHEADS];
    __shared__ int sn_s[256];
    float ern[NHEADS];
#pragma unroll
    for (int hd = 0; hd < NHEADS; hd++) ern[hd] = er[n * NHEADS + hd];
    int wave = tid >> 6, lane = tid & 63;

    float mx[NHEADS] = { -1e30f, -1e30f, -1e30f, -1e30f };
    for (int t = tid; t < cnt; t += 256) {
        int e = esorted[s0 + t]; int sn = src[e];
#pragma unroll
        for (int hd = 0; hd < NHEADS; hd++) {
            float v = el[sn * NHEADS + hd] + ern[hd];
            v = (v >= 0.f) ? v : 0.2f * v;
            mx[hd] = fmaxf(mx[hd], v);
        }
    }
#pragma unroll
    for (int hd = 0; hd < NHEADS; hd++) {
#pragma unroll
        for (int m = 1; m < 64; m <<= 1) mx[hd] = fmaxf(mx[hd], __shfl_xor(mx[hd], m));
    }
    if (lane == 0) { for (int hd = 0; hd < NHEADS; hd++) red[wave][hd] = mx[hd]; }
    __syncthreads();
    if (tid == 0) {
#pragma unroll
        for (int hd = 0; hd < NHEADS; hd++)
            emax_s[hd] = fmaxf(fmaxf(red[0][hd], red[1][hd]), fmaxf(red[2][hd], red[3][hd]));
    }
    __syncthreads();
    float sm[NHEADS] = { 0.f, 0.f, 0.f, 0.f };
    for (int t = tid; t < cnt; t += 256) {
        int e = esorted[s0 + t]; int sn = src[e];
#pragma unroll
        for (int hd = 0; hd < NHEADS; hd++) {
            float v = el[sn * NHEADS + hd] + ern[hd];
            v = (v >= 0.f) ? v : 0.2f * v;
            sm[hd] += expf(v - emax_s[hd]);
        }
    }
#pragma unroll
    for (int hd = 0; hd < NHEADS; hd++) {
#pragma unroll
        for (int m = 1; m < 64; m <<= 1) sm[hd] += __shfl_xor(sm[hd], m);
    }
    __syncthreads();
    if (lane == 0) { for (int hd = 0; hd < NHEADS; hd++) red[wave][hd] = sm[hd]; }
    __syncthreads();
    if (tid == 0) {
#pragma unroll
        for (int hd = 0; hd < NHEADS; hd++)
            den_s[hd] = red[0][hd] + red[1][hd] + red[2][hd] + red[3][hd];
    }
    __syncthreads();
    float acc[NHEADS][3] = {};
    for (int c0 = 0; c0 < cnt; c0 += 256) {
        int t = c0 + tid;
        if (t < cnt) {
            int e = esorted[s0 + t]; int sn = src[e];
            sn_s[tid] = sn;
#pragma unroll
            for (int hd = 0; hd < NHEADS; hd++) {
                float v = el[sn * NHEADS + hd] + ern[hd];
                v = (v >= 0.f) ? v : 0.2f * v;
                alpha_s[tid][hd] = expf(v - emax_s[hd]) / fmaxf(den_s[hd], 1e-9f);
            }
        }
        __syncthreads();
        int cm = cnt - c0; if (cm > 256) cm = 256;
        for (int i = 0; i < cm; i++) {
            int sn = sn_s[i];
            const float* fr = f + (size_t)sn * (NHEADS * HD);
#pragma unroll
            for (int hd = 0; hd < NHEADS; hd++) {
                float a = alpha_s[i][hd];
#pragma unroll
                for (int r = 0; r < 3; r++) acc[hd][r] += a * fr[hd * HD + r * 256 + tid];
            }
        }
        __syncthreads();
    }
#pragma unroll
    for (int r = 0; r < 3; r++) {
        int j = r * 256 + tid;
        float s = 0.f;
#pragma unroll
        for (int hd = 0; hd < NHEADS; hd++) s += acc[hd][r] + gb[hd * HD + j];
        float hv = 0.25f * s;
        hout[(size_t)n * HD + j] = hv;
        hb[(size_t)n * HD + j] = f2bf(hv);
    }
}

// ---------------------------------------------------------------- decoder pieces
__global__ __launch_bounds__(256) void k_ln_gelu_dec(const float* __restrict__ t1,
        ushort* __restrict__ zzb, const float* __restrict__ b1, const float* __restrict__ g,
        const float* __restrict__ be) {
    int m = blockIdx.x, d = blockIdx.y;
    int row = d * NMASK + m;
    int tid = threadIdx.x;
    __shared__ float rA[4], rB[4];
    float v[3]; float s1 = 0.f, s2 = 0.f;
#pragma unroll
    for (int r = 0; r < 3; r++) {
        int c = r * 256 + tid;
        float x = t1[(size_t)row * HD + c] + b1[d * HD + c];
        v[r] = x; s1 += x; s2 += x * x;
    }
#pragma unroll
    for (int mm = 1; mm < 64; mm <<= 1) { s1 += __shfl_xor(s1, mm); s2 += __shfl_xor(s2, mm); }
    int wave = tid >> 6, lane = tid & 63;
    if (lane == 0) { rA[wave] = s1; rB[wave] = s2; }
    __syncthreads();
    float S1 = rA[0] + rA[1] + rA[2] + rA[3];
    float S2 = rB[0] + rB[1] + rB[2] + rB[3];
    float mean = S1 * (1.f / HD);
    float var = S2 * (1.f / HD) - mean * mean;
    float rstd = rsqrtf(var + 1e-5f);
#pragma unroll
    for (int r = 0; r < 3; r++) {
        int c = r * 256 + tid;
        float zn = (v[r] - mean) * rstd * g[d * HD + c] + be[d * HD + c];
        zzb[(size_t)row * HD + c] = f2bf(gelu_f(zn));
    }
}

__global__ __launch_bounds__(256) void k_cos(const float* __restrict__ rec,
        const float* __restrict__ b2, const int* __restrict__ mask_idx,
        const float* __restrict__ ft, const float* __restrict__ fi,
        float* __restrict__ rec_part) {
    int b = blockIdx.x;
    int d = b / NMASK, m = b % NMASK;
    int node = mask_idx[m];
    int tid = threadIdx.x;
    __shared__ float rA[4], rB[4], rC[4];
    const float* rrow = rec + (size_t)b * HD;
    const float* orig = (d == 0 ? ft : fi) + (size_t)node * HD;
    float pro = 0.f, prr = 0.f, poo = 0.f;
#pragma unroll
    for (int r = 0; r < 3; r++) {
        int c = r * 256 + tid;
        float rv = rrow[c] + b2[d * HD + c];
        float o = orig[c];
        pro += rv * o; prr += rv * rv; poo += o * o;
    }
#pragma unroll
    for (int mm = 1; mm < 64; mm <<= 1) {
        pro += __shfl_xor(pro, mm); prr += __shfl_xor(prr, mm); poo += __shfl_xor(poo, mm);
    }
    int wave = tid >> 6, lane = tid & 63;
    if (lane == 0) { rA[wave] = pro; rB[wave] = prr; rC[wave] = poo; }
    __syncthreads();
    if (tid == 0) {
        float P = rA[0] + rA[1] + rA[2] + rA[3];
        float R = rB[0] + rB[1] + rB[2] + rB[3];
        float O = rC[0] + rC[1] + rC[2] + rC[3];
        float denom = fmaxf(sqrtf(R) * sqrtf(O), 1e-8f);
        float cosv = P / denom;
        float t = 1.f - cosv;
        rec_part[b] = (t * t) * (1.f / (float)NMASK);
    }
}

// ---------------------------------------------------------------- SPD: prep (fold b1, stats, bf16)
__global__ __launch_bounds__(256) void k_spd_prep(float* __restrict__ pab,
        const float* __restrict__ b1, ushort* __restrict__ pp_bf,
        float* __restrict__ Svec, float* __restrict__ Qvec) {
    int r = blockIdx.x, tid = threadIdx.x;
    bool isA = r < NN;
    float* row = pab + (size_t)r * HD;
    __shared__ float rA[4], rB[4];
    float vv[3]; float s1 = 0.f, s2 = 0.f;
#pragma unroll
    for (int rr = 0; rr < 3; rr++) {
        int j = rr * 256 + tid;
        float v = row[j];
        if (isA) v += b1[j];
        vv[rr] = v; s1 += v; s2 += v * v;
    }
#pragma unroll
    for (int m = 1; m < 64; m <<= 1) { s1 += __shfl_xor(s1, m); s2 += __shfl_xor(s2, m); }
    int wave = tid >> 6, lane = tid & 63;
    if (lane == 0) { rA[wave] = s1; rB[wave] = s2; }
#pragma unroll
    for (int rr = 0; rr < 3; rr++) {
        int j = rr * 256 + tid;
        if (isA) row[j] = vv[rr];
        pp_bf[(size_t)r * HD + j] = f2bf(vv[rr]);
    }
    __syncthreads();
    if (tid == 0) {
        Svec[r] = rA[0] + rA[1] + rA[2] + rA[3];
        Qvec[r] = rB[0] + rB[1] + rB[2] + rB[3];
    }
}

// ---------------------------------------------------------------- SPD loss (stats precomputed)
__global__ __launch_bounds__(256) void k_spd2(const float* __restrict__ pab,
        const float* __restrict__ Svec, const float* __restrict__ Qvec,
        const float* __restrict__ cross, const float* __restrict__ g,
        const float* __restrict__ be, const float* __restrict__ w2,
        const float* __restrict__ b2, const float* __restrict__ spd,
        float* __restrict__ partials) {
    __shared__ float pa_s[HD], g_s[HD], be_s[HD], w2_s[HD];
    __shared__ float wsum[4];
    int i = blockIdx.x;
    for (int t = threadIdx.x; t < HD; t += 256) {
        pa_s[t] = pab[(size_t)i * HD + t];   // already includes b1
        g_s[t] = g[t]; be_s[t] = be[t]; w2_s[t] = w2[t];
    }
    __syncthreads();
    int wave = threadIdx.x >> 6, lane = threadIdx.x & 63;
    float Sa = Svec[i], Qa = Qvec[i];
    float bacc = 0.f;
    float b2v = b2[0];
    for (int j = blockIdx.y * 4 + wave; j < NN; j += 32) {
        const float* pbj = pab + (size_t)(NN + j) * HD;
        float mean = (Sa + Svec[NN + j]) * (1.f / HD);
        float ex2 = (Qa + Qvec[NN + j] + 2.f * cross[(size_t)i * NN + j]) * (1.f / HD);
        float var = ex2 - mean * mean;
        float rstd = rsqrtf(var + 1e-5f);
        float dot = 0.f;
#pragma unroll
        for (int r = 0; r < 12; r++) {
            int e = r * 64 + lane;
            float z = pa_s[e] + pbj[e];
            float zn = (z - mean) * rstd * g_s[e] + be_s[e];
            dot += gelu_fast(zn) * w2_s[e];
        }
#pragma unroll
        for (int m = 1; m < 64; m <<= 1) dot += __shfl_xor(dot, m);
        if (lane == 0) {
            float d = (dot + b2v) - spd[(size_t)i * NN + j];
            bacc += d * d;
        }
    }
    if (lane == 0) wsum[wave] = bacc;
    __syncthreads();
    if (threadIdx.x == 0) partials[i * 8 + blockIdx.y] = wsum[0] + wsum[1] + wsum[2] + wsum[3];
}

// ---------------------------------------------------------------- output (copy h + final reduce)
__global__ __launch_bounds__(256) void k_out(const float* __restrict__ h,
        const float* __restrict__ rec_part, const float* __restrict__ spd_part,
        float* __restrict__ out) {
    if (blockIdx.x < NN * HD / 256) {
        int i = blockIdx.x * 256 + threadIdx.x;
        out[1 + i] = h[i];
        return;
    }
    __shared__ float rA[4], rB[4];
    int tid = threadIdx.x;
    float sp = 0.f, rc = 0.f;
    for (int t = tid; t < 8 * NN; t += 256) sp += spd_part[t];
    for (int t = tid; t < 2 * NMASK; t += 256) rc += rec_part[t];
#pragma unroll
    for (int m = 1; m < 64; m <<= 1) { sp += __shfl_xor(sp, m); rc += __shfl_xor(rc, m); }
    int wave = tid >> 6, lane = tid & 63;
    if (lane == 0) { rA[wave] = sp; rB[wave] = rc; }
    __syncthreads();
    if (tid == 0) {
        float SP = rA[0] + rA[1] + rA[2] + rA[3];
        float RC = rB[0] + rB[1] + rB[2] + rB[3];
        out[0] = RC + 0.5f * (SP * (1.f / ((float)NN * (float)NN)));
    }
}

// ================================================================ host
extern "C" void kernel_launch(void* const* d_in, const int* in_sizes, int n_in,
                              void* d_out, int out_size, void* d_ws, size_t ws_size,
                              hipStream_t stream) {
    const float* feat_text = (const float*)d_in[0];
    const float* feat_image = (const float*)d_in[1];
    const float* spd_matrix = (const float*)d_in[2];
    const int*   src       = (const int*)d_in[3];
    const int*   dst       = (const int*)d_in[4];
    const int*   mask_idx  = (const int*)d_in[5];
    const float* mask_token = (const float*)d_in[6];
    const float* gate_W = (const float*)d_in[7];
    const float* gate_b = (const float*)d_in[8];
    const float* exp_W1 = (const float*)d_in[9];
    const float* exp_b1 = (const float*)d_in[10];
    const float* exp_g1 = (const float*)d_in[11];
    const float* exp_be1 = (const float*)d_in[12];
    const float* exp_W2 = (const float*)d_in[13];
    const float* exp_b2 = (const float*)d_in[14];
    const float* gat_W  = (const float*)d_in[15];
    const float* gat_al = (const float*)d_in[16];
    const float* gat_ar = (const float*)d_in[17];
    const float* gat_b  = (const float*)d_in[18];
    const float* dec_W1 = (const float*)d_in[19];
    const float* dec_b1 = (const float*)d_in[20];
    const float* dec_g  = (const float*)d_in[21];
    const float* dec_be = (const float*)d_in[22];
    const float* dec_W2 = (const float*)d_in[23];
    const float* dec_b2 = (const float*)d_in[24];
    const float* spd_W1 = (const float*)d_in[25];
    const float* spd_b1 = (const float*)d_in[26];
    const float* spd_g  = (const float*)d_in[27];
    const float* spd_be = (const float*)d_in[28];
    const float* spd_W2 = (const float*)d_in[29];
    const float* spd_b2 = (const float*)d_in[30];
    (void)in_sizes; (void)n_in; (void)ws_size; (void)out_size;

    float* ws = (float*)d_ws;
    size_t off = 0;
    auto alloc = [&](size_t nfl) { float* p = ws + off; off += (nfl + 3) & ~(size_t)3; return p; };
    float* xm   = alloc((size_t)NN * HD);
    float* hA   = alloc((size_t)NN * HD);
    float* hB   = alloc((size_t)NN * HD);
    float* t1   = alloc((size_t)NN * TOPK * HD);     // also decoder t_dec
    float* eo   = alloc((size_t)NN * TOPK * HD);     // also decoder rec
    float* fbuf = alloc((size_t)NN * NHEADS * HD);
    float* el   = alloc(NN * NHEADS);
    float* er   = alloc(NN * NHEADS);
    float* pab  = alloc((size_t)2 * NN * HD);
    float* cross = alloc((size_t)NN * NN);
    float* Svec = alloc(2 * NN);
    float* Qvec = alloc(2 * NN);
    float* topw = alloc(NN * TOPK);
    float* rec_part = alloc(2 * NMASK + 4);
    float* spd_part = alloc(8 * NN);
    int* topi    = (int*)alloc(NN * TOPK);
    int* ecnt    = (int*)alloc(16);
    int* estart  = (int*)alloc(16);
    int* posArr  = (int*)alloc(NN * TOPK);
    int* eofpos  = (int*)alloc(NN * TOPK);
    int* rowlist = (int*)alloc(NN * TOPK);
    int* dec_rs  = (int*)alloc(4);
    int* nstart  = (int*)alloc(NN + 4);
    int* esorted = (int*)alloc(EE);
    int* counts    = (int*)alloc((size_t)NCHUNK * NN);
    int* chunkbase = (int*)alloc((size_t)NCHUNK * NN);
    // bf16 buffers (ushort) — sizes in floats = half the ushort count
    ushort* xm_bf  = (ushort*)alloc((size_t)NN * HD / 2);
    ushort* eh_bf  = (ushort*)alloc((size_t)NN * TOPK * HD / 2);  // also decoder zz_bf
    ushort* hA_bf  = (ushort*)alloc((size_t)NN * HD / 2);
    ushort* hB_bf  = (ushort*)alloc((size_t)NN * HD / 2);
    ushort* pp_bf  = (ushort*)alloc((size_t)2 * NN * HD / 2);
    ushort* expW1t = (ushort*)alloc((size_t)NEXPERT * HD * HD / 2);
    ushort* expW2t = (ushort*)alloc((size_t)NEXPERT * HD * HD / 2);
    ushort* gatWt  = (ushort*)alloc((size_t)NLAYER * NHEADS * HD * HD / 2);
    ushort* spdW1t = (ushort*)alloc((size_t)2 * HD * HD / 2);
    ushort* decW1t = (ushort*)alloc((size_t)2 * HD * HD / 2);
    ushort* decW2t = (ushort*)alloc((size_t)2 * HD * HD / 2);

    // all weight transposes in one launch
    k_transpose_all<<<dim3(19584), dim3(256), 0, stream>>>(
        exp_W1, exp_W2, gat_W, spd_W1, dec_W1, dec_W2,
        expW1t, expW2t, gatWt, spdW1t, decW1t, decW2t);

    // xm = 0.5*(ft+fi) with mask rows, f32+bf16
    k_xm_fused<<<dim3(NN), dim3(256), 0, stream>>>(
        feat_text, feat_image, mask_idx, mask_token, xm, xm_bf);

    // gating + expert grouping
    k_gate<<<dim3(NN), dim3(256), 0, stream>>>(xm, gate_W, gate_b, topi, topw);
    k_moe_meta<<<dim3(1), dim3(256), 0, stream>>>(topi, ecnt, estart, posArr, eofpos,
                                                  rowlist, dec_rs);

    // edge counting sort (dst-stable, deterministic)
    k_hist<<<dim3(NCHUNK), dim3(256), 0, stream>>>(dst, counts);
    k_scan_all<<<dim3(1), dim3(NN), 0, stream>>>(counts, chunkbase, nstart);
    k_rank2<<<dim3(NCHUNK), dim3(256), 0, stream>>>(dst, chunkbase, nstart, esorted);

    // experts
    k_mfma_gemm<<<dim3(HD / 64, 12, NEXPERT), dim3(256), 0, stream>>>(
        xm_bf, expW1t, t1, 0, HD, HD, HD, (long)HD * HD, 0, rowlist, ecnt, estart);
    k_ln_gelu<<<dim3(NN * TOPK), dim3(256), 0, stream>>>(t1, eh_bf, exp_b1, exp_g1, exp_be1, eofpos);
    k_mfma_gemm<<<dim3(HD / 64, 12, NEXPERT), dim3(256), 0, stream>>>(
        eh_bf, expW2t, eo, 0, HD, HD, HD, (long)HD * HD, 0, nullptr, ecnt, estart);
    k_combine_moe<<<dim3(NN), dim3(256), 0, stream>>>(eo, exp_b2, topi, topw, posArr, hA, hA_bf);

    // GAT layers
    float* hcur = hA; float* hnxt = hB;
    ushort* hcur_bf = hA_bf; ushort* hnxt_bf = hB_bf;
    for (int l = 0; l < NLAYER; l++) {
        k_mfma_gemm<<<dim3(NHEADS * HD / 64, NN / 64, 1), dim3(256), 0, stream>>>(
            hcur_bf, gatWt + (size_t)l * NHEADS * HD * HD, fbuf,
            NN, HD, HD, NHEADS * HD, 0, 0, nullptr, nullptr, nullptr);
        k_el_er<<<dim3(NN), dim3(256), 0, stream>>>(
            fbuf, gat_al + (size_t)l * NHEADS * HD, gat_ar + (size_t)l * NHEADS * HD, el, er);
        k_gat_agg<<<dim3(NN), dim3(256), 0, stream>>>(
            fbuf, el, er, src, esorted, nstart, gat_b + (size_t)l * NHEADS * HD, hnxt, hnxt_bf);
        float* t = hcur; hcur = hnxt; hnxt = t;
        ushort* tb = hcur_bf; hcur_bf = hnxt_bf; hnxt_bf = tb;
    }

    // decoder recon loss (gather fused into GEMM via rowsA)
    k_mfma_gemm<<<dim3(HD / 64, 1, 2), dim3(256), 0, stream>>>(
        hcur_bf, decW1t, t1, NMASK, HD, HD, HD, (long)HD * HD, (long)NMASK * HD,
        mask_idx, nullptr, nullptr);
    k_ln_gelu_dec<<<dim3(NMASK, 2), dim3(256), 0, stream>>>(t1, eh_bf, dec_b1, dec_g, dec_be);
    k_mfma_gemm<<<dim3(HD / 64, 1, 2), dim3(256), 0, stream>>>(
        eh_bf, decW2t, eo, NMASK, HD, HD, HD, (long)HD * HD, 0,
        nullptr, nullptr, dec_rs);
    k_cos<<<dim3(2 * NMASK), dim3(256), 0, stream>>>(
        eo, dec_b2, mask_idx, feat_text, feat_image, rec_part);

    // SPD: projections -> prep (fold b1, stats, bf16) -> cross GEMM -> loss
    k_mfma_gemm<<<dim3(HD / 64, NN / 64, 2), dim3(256), 0, stream>>>(
        hcur_bf, spdW1t, pab, NN, HD, HD, HD, (long)HD * HD, (long)NN * HD,
        nullptr, nullptr, nullptr);
    k_spd_prep<<<dim3(2 * NN), dim3(256), 0, stream>>>(pab, spd_b1, pp_bf, Svec, Qvec);
    k_mfma_gemm<<<dim3(NN / 64, NN / 64, 1), dim3(256), 0, stream>>>(
        pp_bf, pp_bf + (size_t)NN * HD, cross, NN, HD, HD, NN, 0, 0,
        nullptr, nullptr, nullptr);
    k_spd2<<<dim3(NN, 8), dim3(256), 0, stream>>>(
        pab, Svec, Qvec, cross, spd_g, spd_be, spd_W2, spd_b2, spd_matrix, spd_part);

    // output: copy h + final loss
    k_out<<<dim3(NN * HD / 256 + 1), dim3(256), 0, stream>>>(
        hcur, rec_part, spd_part, (float*)d_out);
}

// Round 5
// 361.100 us; speedup vs baseline: 2.5544x; 1.0229x over previous
//
#include <hip/hip_runtime.h>
#include <hip/hip_bf16.h>
#include <math.h>

#define NN 384
#define HD 768
#define EE 12288
#define NCHUNK (EE / 256)
#define NEXPERT 8
#define TOPK 2
#define NLAYER 3
#define NHEADS 4
#define NMASK 38

typedef __attribute__((ext_vector_type(8))) short short8v;
typedef __attribute__((ext_vector_type(4))) float f32x4;
typedef __attribute__((ext_vector_type(2))) float f32x2;
typedef __attribute__((ext_vector_type(4))) int int4v;

__device__ __forceinline__ float gelu_f(float x) {
    return x * 0.5f * (1.f + erff(x * 0.70710678118654752440f));
}

__device__ __forceinline__ ushort f2bf(float x) {
    unsigned u = __float_as_uint(x);
    u += 0x7fffu + ((u >> 16) & 1u);
    return (ushort)(u >> 16);
}

// ---------------------------------------------------------------- fused xm + gate
__global__ __launch_bounds__(256) void k_xm_gate(const float* __restrict__ a,
        const float* __restrict__ b, const int* __restrict__ mask_idx,
        const float* __restrict__ mt, ushort* __restrict__ xm_bf,
        const float* __restrict__ gW, const float* __restrict__ gb,
        int* __restrict__ topi, float* __restrict__ topw) {
    int n = blockIdx.x, tid = threadIdx.x;
    __shared__ float xs[HD];
    __shared__ int ism;
    __shared__ float logits[NEXPERT];
    if (tid == 0) ism = 0;
    __syncthreads();
    if (tid < NMASK && mask_idx[tid] == n) ism = 1;
    __syncthreads();
#pragma unroll
    for (int r = 0; r < 3; r++) {
        int j = r * 256 + tid;
        float v = ism ? mt[j] : 0.5f * (a[(size_t)n * HD + j] + b[(size_t)n * HD + j]);
        xs[j] = v;
        xm_bf[(size_t)n * HD + j] = f2bf(v);
    }
    __syncthreads();
    int grp = tid >> 5;
    int l32 = tid & 31;
    float p = 0.f;
    for (int dd = l32; dd < HD; dd += 32) p += xs[dd] * gW[dd * NEXPERT + grp];
#pragma unroll
    for (int m = 1; m < 32; m <<= 1) p += __shfl_xor(p, m, 32);
    if (l32 == 0) logits[grp] = p + gb[grp];
    __syncthreads();
    if (tid == 0) {
        float mx = logits[0];
#pragma unroll
        for (int e = 1; e < NEXPERT; e++) mx = fmaxf(mx, logits[e]);
        float sm[NEXPERT]; float s = 0.f;
#pragma unroll
        for (int e = 0; e < NEXPERT; e++) { sm[e] = expf(logits[e] - mx); s += sm[e]; }
#pragma unroll
        for (int e = 0; e < NEXPERT; e++) sm[e] /= s;
        int i0 = 0; float b0 = sm[0];
#pragma unroll
        for (int e = 1; e < NEXPERT; e++) if (sm[e] > b0) { b0 = sm[e]; i0 = e; }
        int i1 = -1; float b1v = -1.f;
#pragma unroll
        for (int e = 0; e < NEXPERT; e++) if (e != i0 && sm[e] > b1v) { b1v = sm[e]; i1 = e; }
        float ssum = b0 + b1v;
        topi[n * 2] = i0; topi[n * 2 + 1] = i1;
        topw[n * 2] = b0 / ssum; topw[n * 2 + 1] = b1v / ssum;
    }
}

// ---------------------------------------------------------------- all weight transposes
// f32 [z][K][N] -> bf16 [z][N][K], 32x32 tiles, 6 segments flattened into one grid.
__global__ __launch_bounds__(256) void k_transpose_all(
        const float* __restrict__ w1, const float* __restrict__ w2,
        const float* __restrict__ gw, const float* __restrict__ sw,
        const float* __restrict__ dw1, const float* __restrict__ dw2,
        ushort* __restrict__ o1, ushort* __restrict__ o2, ushort* __restrict__ og,
        ushort* __restrict__ os, ushort* __restrict__ od1, ushort* __restrict__ od2) {
    int b = blockIdx.x;
    const float* src; ushort* dst; int N, loc, tilesX;
    if (b < 4608)       { src = w1;  dst = o1;  N = HD;     loc = b;         tilesX = 24; }
    else if (b < 9216)  { src = w2;  dst = o2;  N = HD;     loc = b - 4608;  tilesX = 24; }
    else if (b < 16128) { src = gw;  dst = og;  N = 4 * HD; loc = b - 9216;  tilesX = 96; }
    else if (b < 17280) { src = sw;  dst = os;  N = HD;     loc = b - 16128; tilesX = 24; }
    else if (b < 18432) { src = dw1; dst = od1; N = HD;     loc = b - 17280; tilesX = 24; }
    else                { src = dw2; dst = od2; N = HD;     loc = b - 18432; tilesX = 24; }
    const int K = HD;
    int tilesPerZ = tilesX * 24;
    int z = loc / tilesPerZ;
    int rem = loc - z * tilesPerZ;
    int ty = rem / tilesX, tx = rem - ty * tilesX;
    const float* inz = src + (size_t)z * K * N;
    ushort* outz = dst + (size_t)z * K * N;
    int n0 = tx * 32, k0 = ty * 32;

    __shared__ float t[32][36];
    int r = threadIdx.x >> 3, c4 = (threadIdx.x & 7) * 4;
    float4 v = *reinterpret_cast<const float4*>(inz + (size_t)(k0 + r) * N + n0 + c4);
    t[r][c4] = v.x; t[r][c4 + 1] = v.y; t[r][c4 + 2] = v.z; t[r][c4 + 3] = v.w;
    __syncthreads();
    int orow = n0 + r;
    uint2 p;
    ushort b0 = f2bf(t[c4 + 0][r]);
    ushort b1 = f2bf(t[c4 + 1][r]);
    ushort b2 = f2bf(t[c4 + 2][r]);
    ushort b3 = f2bf(t[c4 + 3][r]);
    p.x = (unsigned)b0 | ((unsigned)b1 << 16);
    p.y = (unsigned)b2 | ((unsigned)b3 << 16);
    *reinterpret_cast<uint2*>(outz + (size_t)orow * K + k0 + c4) = p;
}

// ---------------------------------------------------------------- MoE meta (single block)
__global__ __launch_bounds__(256) void k_moe_meta(const int* __restrict__ topi,
        int* __restrict__ ecnt, int* __restrict__ estart, int* __restrict__ posArr,
        int* __restrict__ eofpos, int* __restrict__ rowlist, int* __restrict__ dec_rs) {
    __shared__ int ti[NN * TOPK];
    __shared__ int cnt[NEXPERT];
    __shared__ int est[NEXPERT + 1];
    int tid = threadIdx.x;
    if (tid < NEXPERT) cnt[tid] = 0;
    __syncthreads();
    for (int a = tid; a < NN * TOPK; a += 256) ti[a] = topi[a];
    __syncthreads();
    for (int a = tid; a < NN * TOPK; a += 256) atomicAdd(&cnt[ti[a]], 1);
    __syncthreads();
    if (tid == 0) {
        int s = 0;
        for (int e = 0; e < NEXPERT; e++) { est[e] = s; s += cnt[e]; }
        est[NEXPERT] = s;
        dec_rs[0] = 0; dec_rs[1] = NMASK;
    }
    __syncthreads();
    if (tid < NEXPERT) { ecnt[tid] = cnt[tid]; estart[tid] = est[tid]; }
    if (tid == 0) estart[NEXPERT] = est[NEXPERT];
    for (int a = tid; a < NN * TOPK; a += 256) {
        int e = ti[a]; int rank = 0;
        for (int a2 = 0; a2 < a; a2++) rank += (ti[a2] == e) ? 1 : 0;
        int p = est[e] + rank;
        posArr[a] = p; eofpos[p] = e; rowlist[p] = a >> 1;
    }
}

// ---------------------------------------------------------------- edge counting sort
__global__ __launch_bounds__(256) void k_hist(const int* __restrict__ dst,
                                              int* __restrict__ counts) {
    __shared__ int h[NN];
    int c = blockIdx.x;
    for (int i = threadIdx.x; i < NN; i += 256) h[i] = 0;
    __syncthreads();
    atomicAdd(&h[dst[c * 256 + threadIdx.x]], 1);
    __syncthreads();
    for (int i = threadIdx.x; i < NN; i += 256) counts[c * NN + i] = h[i];
}

__global__ __launch_bounds__(NN) void k_scan_all(const int* __restrict__ counts,
        int* __restrict__ chunkbase, int* __restrict__ nstart) {
    __shared__ int tot[NN];
    int n = threadIdx.x;
    int s = 0;
    for (int c = 0; c < NCHUNK; c++) { chunkbase[c * NN + n] = s; s += counts[c * NN + n]; }
    tot[n] = s;
    __syncthreads();
    for (int off = 1; off < NN; off <<= 1) {
        int v = tot[n];
        int add = (n >= off) ? tot[n - off] : 0;
        __syncthreads();
        tot[n] = v + add;
        __syncthreads();
    }
    nstart[n + 1] = tot[n];
    if (n == 0) nstart[0] = 0;
}

__global__ __launch_bounds__(256) void k_rank2(const int* __restrict__ dst,
        const int* __restrict__ chunkbase, const int* __restrict__ nstart,
        int* __restrict__ esorted) {
    __shared__ int ds[256];
    int c = blockIdx.x;
    int e = c * 256 + threadIdx.x;
    int d = dst[e];
    ds[threadIdx.x] = d;
    __syncthreads();
    int r = 0;
    for (int i = 0; i < threadIdx.x; i++) r += (ds[i] == d) ? 1 : 0;
    esorted[nstart[d] + chunkbase[c * NN + d] + r] = e;
}

// ---------------------------------------------------------------- bf16 MFMA GEMM
__device__ __forceinline__ short8v ldfrag(const ushort* s, int r, int kb) {
    int c = kb ^ (r & 7);
    return *reinterpret_cast<const short8v*>(s + r * 64 + c * 8);
}

__global__ __launch_bounds__(256) void k_mfma_gemm(
        const ushort* __restrict__ A, const ushort* __restrict__ Bt, float* __restrict__ C,
        int M, int K, int lda, int ldc, long strideBt, long strideC,
        const int* __restrict__ rowsA, const int* __restrict__ Ms,
        const int* __restrict__ rowStarts) {
    int z = blockIdx.z;
    int Meff = Ms ? Ms[z] : M;
    int row0 = blockIdx.y * 64;
    if (row0 >= Meff) return;
    int col0 = blockIdx.x * 64;
    int rowbase = rowStarts ? rowStarts[z] : 0;
    const ushort* Btz = Bt + (size_t)z * strideBt;
    float* Cz = C + (size_t)rowbase * ldc + (size_t)z * strideC;
    const int* rz = rowsA ? (rowsA + rowbase) : nullptr;

    __shared__ ushort Asm[64 * 64];
    __shared__ ushort Bsm[64 * 64];

    int tid = threadIdx.x;
    int w = tid >> 6, lane = tid & 63;
    int wr = w >> 1, wc = w & 1;
    int l15 = lane & 15, lq = lane >> 4;

    f32x4 acc[2][2];
#pragma unroll
    for (int i = 0; i < 2; i++)
#pragma unroll
        for (int j = 0; j < 2; j++) acc[i][j] = (f32x4){0.f, 0.f, 0.f, 0.f};

    for (int k0 = 0; k0 < K; k0 += 64) {
#pragma unroll
        for (int ii = 0; ii < 2; ii++) {
            int i = tid + ii * 256;
            int r = i >> 3, c = i & 7;
            int cs = c ^ (r & 7);
            int4v av = (int4v){0, 0, 0, 0};
            int grow = row0 + r;
            if (grow < Meff) {
                int srow = rz ? rz[grow] : (rowbase + grow);
                av = *reinterpret_cast<const int4v*>(A + (size_t)srow * lda + k0 + c * 8);
            }
            *reinterpret_cast<int4v*>(&Asm[r * 64 + cs * 8]) = av;
            int4v bv = *reinterpret_cast<const int4v*>(Btz + (size_t)(col0 + r) * K + k0 + c * 8);
            *reinterpret_cast<int4v*>(&Bsm[r * 64 + cs * 8]) = bv;
        }
        __syncthreads();
#pragma unroll
        for (int ks = 0; ks < 2; ks++) {
            int kb = ks * 4 + lq;
            short8v a0 = ldfrag(Asm, wr * 32 + l15, kb);
            short8v a1 = ldfrag(Asm, wr * 32 + 16 + l15, kb);
            short8v b0 = ldfrag(Bsm, wc * 32 + l15, kb);
            short8v b1 = ldfrag(Bsm, wc * 32 + 16 + l15, kb);
            acc[0][0] = __builtin_amdgcn_mfma_f32_16x16x32_bf16(a0, b0, acc[0][0], 0, 0, 0);
            acc[0][1] = __builtin_amdgcn_mfma_f32_16x16x32_bf16(a0, b1, acc[0][1], 0, 0, 0);
            acc[1][0] = __builtin_amdgcn_mfma_f32_16x16x32_bf16(a1, b0, acc[1][0], 0, 0, 0);
            acc[1][1] = __builtin_amdgcn_mfma_f32_16x16x32_bf16(a1, b1, acc[1][1], 0, 0, 0);
        }
        __syncthreads();
    }
#pragma unroll
    for (int ai = 0; ai < 2; ai++)
#pragma unroll
        for (int bi = 0; bi < 2; bi++) {
            int rbase = row0 + wr * 32 + ai * 16 + (lq << 2);
            int cc = col0 + wc * 32 + bi * 16 + l15;
#pragma unroll
            for (int r = 0; r < 4; r++) {
                int rr = rbase + r;
                if (rr < Meff) Cz[(size_t)rr * ldc + cc] = acc[ai][bi][r];
            }
        }
}

// ---------------------------------------------------------------- expert LN+GELU -> bf16
__global__ __launch_bounds__(256) void k_ln_gelu(const float* __restrict__ t1,
        ushort* __restrict__ ehb, const float* __restrict__ b1, const float* __restrict__ g,
        const float* __restrict__ be, const int* __restrict__ eofpos) {
    int row = blockIdx.x;
    int e = eofpos[row];
    int tid = threadIdx.x;
    __shared__ float rA[4], rB[4];
    float v[3]; float s1 = 0.f, s2 = 0.f;
#pragma unroll
    for (int r = 0; r < 3; r++) {
        int c = r * 256 + tid;
        float x = t1[(size_t)row * HD + c] + b1[e * HD + c];
        v[r] = x; s1 += x; s2 += x * x;
    }
#pragma unroll
    for (int m = 1; m < 64; m <<= 1) { s1 += __shfl_xor(s1, m); s2 += __shfl_xor(s2, m); }
    int wave = tid >> 6, lane = tid & 63;
    if (lane == 0) { rA[wave] = s1; rB[wave] = s2; }
    __syncthreads();
    float S1 = rA[0] + rA[1] + rA[2] + rA[3];
    float S2 = rB[0] + rB[1] + rB[2] + rB[3];
    float mean = S1 * (1.f / HD);
    float var = S2 * (1.f / HD) - mean * mean;
    float rstd = rsqrtf(var + 1e-5f);
#pragma unroll
    for (int r = 0; r < 3; r++) {
        int c = r * 256 + tid;
        float zn = (v[r] - mean) * rstd * g[e * HD + c] + be[e * HD + c];
        ehb[(size_t)row * HD + c] = f2bf(gelu_f(zn));
    }
}

__global__ void k_combine_moe(const float* __restrict__ eo, const float* __restrict__ b2,
        const int* __restrict__ topi, const float* __restrict__ topw,
        const int* __restrict__ posArr, float* __restrict__ h, ushort* __restrict__ hb) {
    int n = blockIdx.x;
    int tid = threadIdx.x;
    int e0 = topi[n * 2], e1 = topi[n * 2 + 1];
    float w0 = topw[n * 2], w1 = topw[n * 2 + 1];
    int p0 = posArr[n * 2], p1 = posArr[n * 2 + 1];
    for (int j = tid; j < HD; j += 256) {
        float v0 = eo[(size_t)p0 * HD + j] + b2[e0 * HD + j];
        float v1 = eo[(size_t)p1 * HD + j] + b2[e1 * HD + j];
        float hv = w0 * v0 + w1 * v1;
        h[(size_t)n * HD + j] = hv;
        hb[(size_t)n * HD + j] = f2bf(hv);
    }
}

// ---------------------------------------------------------------- GAT
__global__ __launch_bounds__(256) void k_el_er(const float* __restrict__ f,
        const float* __restrict__ al, const float* __restrict__ ar,
        float* __restrict__ el, float* __restrict__ er) {
    int n = blockIdx.x;
    int hd = threadIdx.x >> 6, lane = threadIdx.x & 63;
    const float* fr = f + ((size_t)n * NHEADS + hd) * HD;
    float pl = 0.f, pr = 0.f;
    for (int j = lane; j < HD; j += 64) {
        float fv = fr[j];
        pl += fv * al[hd * HD + j];
        pr += fv * ar[hd * HD + j];
    }
#pragma unroll
    for (int m = 1; m < 64; m <<= 1) { pl += __shfl_xor(pl, m); pr += __shfl_xor(pr, m); }
    if (lane == 0) { el[n * NHEADS + hd] = pl; er[n * NHEADS + hd] = pr; }
}

__global__ __launch_bounds__(256) void k_gat_agg(const float* __restrict__ f,
        const float* __restrict__ el, const float* __restrict__ er,
        const int* __restrict__ src, const int* __restrict__ esorted,
        const int* __restrict__ nstart, const float* __restrict__ gb,
        float* __restrict__ hout, ushort* __restrict__ hb) {
    int n = blockIdx.x;
    int s0 = nstart[n], cnt = nstart[n + 1] - s0;
    int tid = threadIdx.x;
    __shared__ float red[4][NHEADS];
    __shared__ float emax_s[NHEADS], den_s[NHEADS];
    __shared__ float alpha_s[256][NHEADS];
    __shared__ int sn_s[256];
    float ern[NHEADS];
#pragma unroll
    for (int hd = 0; hd < NHEADS; hd++) ern[hd] = er[n * NHEADS + hd];
    int wave = tid >> 6, lane = tid & 63;

    float mx[NHEADS] = { -1e30f, -1e30f, -1e30f, -1e30f };
    for (int t = tid; t < cnt; t += 256) {
        int e = esorted[s0 + t]; int sn = src[e];
#pragma unroll
        for (int hd = 0; hd < NHEADS; hd++) {
            float v = el[sn * NHEADS + hd] + ern[hd];
            v = (v >= 0.f) ? v : 0.2f * v;
            mx[hd] = fmaxf(mx[hd], v);
        }
    }
#pragma unroll
    for (int hd = 0; hd < NHEADS; hd++) {
#pragma unroll
        for (int m = 1; m < 64; m <<= 1) mx[hd] = fmaxf(mx[hd], __shfl_xor(mx[hd], m));
    }
    if (lane == 0) { for (int hd = 0; hd < NHEADS; hd++) red[wave][hd] = mx[hd]; }
    __syncthreads();
    if (tid == 0) {
#pragma unroll
        for (int hd = 0; hd < NHEADS; hd++)
            emax_s[hd] = fmaxf(fmaxf(red[0][hd], red[1][hd]), fmaxf(red[2][hd], red[3][hd]));
    }
    __syncthreads();
    float sm[NHEADS] = { 0.f, 0.f, 0.f, 0.f };
    for (int t = tid; t < cnt; t += 256) {
        int e = esorted[s0 + t]; int sn = src[e];
#pragma unroll
        for (int hd = 0; hd < NHEADS; hd++) {
            float v = el[sn * NHEADS + hd] + ern[hd];
            v = (v >= 0.f) ? v : 0.2f * v;
            sm[hd] += expf(v - emax_s[hd]);
        }
    }
#pragma unroll
    for (int hd = 0; hd < NHEADS; hd++) {
#pragma unroll
        for (int m = 1; m < 64; m <<= 1) sm[hd] += __shfl_xor(sm[hd], m);
    }
    __syncthreads();
    if (lane == 0) { for (int hd = 0; hd < NHEADS; hd++) red[wave][hd] = sm[hd]; }
    __syncthreads();
    if (tid == 0) {
#pragma unroll
        for (int hd = 0; hd < NHEADS; hd++)
            den_s[hd] = red[0][hd] + red[1][hd] + red[2][hd] + red[3][hd];
    }
    __syncthreads();
    float acc[NHEADS][3] = {};
    for (int c0 = 0; c0 < cnt; c0 += 256) {
        int t = c0 + tid;
        if (t < cnt) {
            int e = esorted[s0 + t]; int sn = src[e];
            sn_s[tid] = sn;
#pragma unroll
            for (int hd = 0; hd < NHEADS; hd++) {
                float v = el[sn * NHEADS + hd] + ern[hd];
                v = (v >= 0.f) ? v : 0.2f * v;
                alpha_s[tid][hd] = expf(v - emax_s[hd]) / fmaxf(den_s[hd], 1e-9f);
            }
        }
        __syncthreads();
        int cm = cnt - c0; if (cm > 256) cm = 256;
        for (int i = 0; i < cm; i++) {
            int sn = sn_s[i];
            const float* fr = f + (size_t)sn * (NHEADS * HD);
#pragma unroll
            for (int hd = 0; hd < NHEADS; hd++) {
                float a = alpha_s[i][hd];
#pragma unroll
                for (int r = 0; r < 3; r++) acc[hd][r] += a * fr[hd * HD + r * 256 + tid];
            }
        }
        __syncthreads();
    }
#pragma unroll
    for (int r = 0; r < 3; r++) {
        int j = r * 256 + tid;
        float s = 0.f;
#pragma unroll
        for (int hd = 0; hd < NHEADS; hd++) s += acc[hd][r] + gb[hd * HD + j];
        float hv = 0.25f * s;
        hout[(size_t)n * HD + j] = hv;
        hb[(size_t)n * HD + j] = f2bf(hv);
    }
}

// ---------------------------------------------------------------- decoder pieces
__global__ __launch_bounds__(256) void k_ln_gelu_dec(const float* __restrict__ t1,
        ushort* __restrict__ zzb, const float* __restrict__ b1, const float* __restrict__ g,
        const float* __restrict__ be) {
    int m = blockIdx.x, d = blockIdx.y;
    int row = d * NMASK + m;
    int tid = threadIdx.x;
    __shared__ float rA[4], rB[4];
    float v[3]; float s1 = 0.f, s2 = 0.f;
#pragma unroll
    for (int r = 0; r < 3; r++) {
        int c = r * 256 + tid;
        float x = t1[(size_t)row * HD + c] + b1[d * HD + c];
        v[r] = x; s1 += x; s2 += x * x;
    }
#pragma unroll
    for (int mm = 1; mm < 64; mm <<= 1) { s1 += __shfl_xor(s1, mm); s2 += __shfl_xor(s2, mm); }
    int wave = tid >> 6, lane = tid & 63;
    if (lane == 0) { rA[wave] = s1; rB[wave] = s2; }
    __syncthreads();
    float S1 = rA[0] + rA[1] + rA[2] + rA[3];
    float S2 = rB[0] + rB[1] + rB[2] + rB[3];
    float mean = S1 * (1.f / HD);
    float var = S2 * (1.f / HD) - mean * mean;
    float rstd = rsqrtf(var + 1e-5f);
#pragma unroll
    for (int r = 0; r < 3; r++) {
        int c = r * 256 + tid;
        float zn = (v[r] - mean) * rstd * g[d * HD + c] + be[d * HD + c];
        zzb[(size_t)row * HD + c] = f2bf(gelu_f(zn));
    }
}

__global__ __launch_bounds__(256) void k_cos(const float* __restrict__ rec,
        const float* __restrict__ b2, const int* __restrict__ mask_idx,
        const float* __restrict__ ft, const float* __restrict__ fi,
        float* __restrict__ rec_part) {
    int b = blockIdx.x;
    int d = b / NMASK, m = b % NMASK;
    int node = mask_idx[m];
    int tid = threadIdx.x;
    __shared__ float rA[4], rB[4], rC[4];
    const float* rrow = rec + (size_t)b * HD;
    const float* orig = (d == 0 ? ft : fi) + (size_t)node * HD;
    float pro = 0.f, prr = 0.f, poo = 0.f;
#pragma unroll
    for (int r = 0; r < 3; r++) {
        int c = r * 256 + tid;
        float rv = rrow[c] + b2[d * HD + c];
        float o = orig[c];
        pro += rv * o; prr += rv * rv; poo += o * o;
    }
#pragma unroll
    for (int mm = 1; mm < 64; mm <<= 1) {
        pro += __shfl_xor(pro, mm); prr += __shfl_xor(prr, mm); poo += __shfl_xor(poo, mm);
    }
    int wave = tid >> 6, lane = tid & 63;
    if (lane == 0) { rA[wave] = pro; rB[wave] = prr; rC[wave] = poo; }
    __syncthreads();
    if (tid == 0) {
        float P = rA[0] + rA[1] + rA[2] + rA[3];
        float R = rB[0] + rB[1] + rB[2] + rB[3];
        float O = rC[0] + rC[1] + rC[2] + rC[3];
        float denom = fmaxf(sqrtf(R) * sqrtf(O), 1e-8f);
        float cosv = P / denom;
        float t = 1.f - cosv;
        rec_part[b] = (t * t) * (1.f / (float)NMASK);
    }
}

// ---------------------------------------------------------------- SPD: prep (fold b1, stats, bf16)
__global__ __launch_bounds__(256) void k_spd_prep(float* __restrict__ pab,
        const float* __restrict__ b1, ushort* __restrict__ pp_bf,
        float* __restrict__ Svec, float* __restrict__ Qvec) {
    int r = blockIdx.x, tid = threadIdx.x;
    bool isA = r < NN;
    float* row = pab + (size_t)r * HD;
    __shared__ float rA[4], rB[4];
    float vv[3]; float s1 = 0.f, s2 = 0.f;
#pragma unroll
    for (int rr = 0; rr < 3; rr++) {
        int j = rr * 256 + tid;
        float v = row[j];
        if (isA) v += b1[j];
        vv[rr] = v; s1 += v; s2 += v * v;
    }
#pragma unroll
    for (int m = 1; m < 64; m <<= 1) { s1 += __shfl_xor(s1, m); s2 += __shfl_xor(s2, m); }
    int wave = tid >> 6, lane = tid & 63;
    if (lane == 0) { rA[wave] = s1; rB[wave] = s2; }
#pragma unroll
    for (int rr = 0; rr < 3; rr++) {
        int j = rr * 256 + tid;
        if (isA) row[j] = vv[rr];
        pp_bf[(size_t)r * HD + j] = f2bf(vv[rr]);
    }
    __syncthreads();
    if (tid == 0) {
        Svec[r] = rA[0] + rA[1] + rA[2] + rA[3];
        Qvec[r] = rB[0] + rB[1] + rB[2] + rB[3];
    }
}

// ---------------------------------------------------------------- SPD loss (packed f32x2 math)
// gelu_fast in log2 domain: u = x*(C1 + C2*x^2), gelu = x / (1 + 2^(-u))
#define GC1 2.3022085f
#define GC2 0.10294429f
__global__ __launch_bounds__(256) void k_spd2(const float* __restrict__ pab,
        const float* __restrict__ Svec, const float* __restrict__ Qvec,
        const float* __restrict__ cross, const float* __restrict__ g,
        const float* __restrict__ be, const float* __restrict__ w2,
        const float* __restrict__ b2, const float* __restrict__ spd,
        float* __restrict__ partials) {
    __shared__ f32x2 pa_s[HD / 2], g_s[HD / 2], be_s[HD / 2], w2_s[HD / 2];
    __shared__ float wsum[4];
    int i = blockIdx.x;
    const f32x2* paP = reinterpret_cast<const f32x2*>(pab + (size_t)i * HD);
    const f32x2* gP = reinterpret_cast<const f32x2*>(g);
    const f32x2* beP = reinterpret_cast<const f32x2*>(be);
    const f32x2* w2P = reinterpret_cast<const f32x2*>(w2);
    for (int t = threadIdx.x; t < HD / 2; t += 256) {
        pa_s[t] = paP[t];   // already includes b1
        g_s[t] = gP[t]; be_s[t] = beP[t]; w2_s[t] = w2P[t];
    }
    __syncthreads();
    int wave = threadIdx.x >> 6, lane = threadIdx.x & 63;
    float Sa = Svec[i], Qa = Qvec[i];
    float bacc = 0.f;
    float b2v = b2[0];
    for (int j = blockIdx.y * 4 + wave; j < NN; j += 32) {
        const f32x2* pbj = reinterpret_cast<const f32x2*>(pab + (size_t)(NN + j) * HD);
        float mean = (Sa + Svec[NN + j]) * (1.f / HD);
        float ex2 = (Qa + Qvec[NN + j] + 2.f * cross[(size_t)i * NN + j]) * (1.f / HD);
        float var = ex2 - mean * mean;
        float rstd = rsqrtf(var + 1e-5f);
        f32x2 rstd2 = (f32x2){rstd, rstd};
        float nmr = -mean * rstd;
        f32x2 nmr2 = (f32x2){nmr, nmr};
        f32x2 dot2 = (f32x2){0.f, 0.f};
#pragma unroll
        for (int r = 0; r < 6; r++) {
            int e = r * 64 + lane;
            f32x2 z = pa_s[e] + pbj[e];
            f32x2 u = z * rstd2 + nmr2;
            f32x2 zn = u * g_s[e] + be_s[e];
            f32x2 t2 = zn * zn;
            f32x2 p = t2 * (f32x2){GC2, GC2} + (f32x2){GC1, GC1};
            f32x2 ua = zn * p;
            float e0 = __builtin_amdgcn_exp2f(-ua.x);
            float e1 = __builtin_amdgcn_exp2f(-ua.y);
            f32x2 rr = (f32x2){__builtin_amdgcn_rcpf(1.f + e0),
                               __builtin_amdgcn_rcpf(1.f + e1)};
            f32x2 gl = zn * rr;
            dot2 = gl * w2_s[e] + dot2;
        }
        float dot = dot2.x + dot2.y;
#pragma unroll
        for (int m = 1; m < 64; m <<= 1) dot += __shfl_xor(dot, m);
        if (lane == 0) {
            float d = (dot + b2v) - spd[(size_t)i * NN + j];
            bacc += d * d;
        }
    }
    if (lane == 0) wsum[wave] = bacc;
    __syncthreads();
    if (threadIdx.x == 0) partials[i * 8 + blockIdx.y] = wsum[0] + wsum[1] + wsum[2] + wsum[3];
}

// ---------------------------------------------------------------- output (copy h + final reduce)
__global__ __launch_bounds__(256) void k_out(const float* __restrict__ h,
        const float* __restrict__ rec_part, const float* __restrict__ spd_part,
        float* __restrict__ out) {
    if (blockIdx.x < NN * HD / 256) {
        int i = blockIdx.x * 256 + threadIdx.x;
        out[1 + i] = h[i];
        return;
    }
    __shared__ float rA[4], rB[4];
    int tid = threadIdx.x;
    float sp = 0.f, rc = 0.f;
    for (int t = tid; t < 8 * NN; t += 256) sp += spd_part[t];
    for (int t = tid; t < 2 * NMASK; t += 256) rc += rec_part[t];
#pragma unroll
    for (int m = 1; m < 64; m <<= 1) { sp += __shfl_xor(sp, m); rc += __shfl_xor(rc, m); }
    int wave = tid >> 6, lane = tid & 63;
    if (lane == 0) { rA[wave] = sp; rB[wave] = rc; }
    __syncthreads();
    if (tid == 0) {
        float SP = rA[0] + rA[1] + rA[2] + rA[3];
        float RC = rB[0] + rB[1] + rB[2] + rB[3];
        out[0] = RC + 0.5f * (SP * (1.f / ((float)NN * (float)NN)));
    }
}

// ================================================================ host
extern "C" void kernel_launch(void* const* d_in, const int* in_sizes, int n_in,
                              void* d_out, int out_size, void* d_ws, size_t ws_size,
                              hipStream_t stream) {
    const float* feat_text = (const float*)d_in[0];
    const float* feat_image = (const float*)d_in[1];
    const float* spd_matrix = (const float*)d_in[2];
    const int*   src       = (const int*)d_in[3];
    const int*   dst       = (const int*)d_in[4];
    const int*   mask_idx  = (const int*)d_in[5];
    const float* mask_token = (const float*)d_in[6];
    const float* gate_W = (const float*)d_in[7];
    const float* gate_b = (const float*)d_in[8];
    const float* exp_W1 = (const float*)d_in[9];
    const float* exp_b1 = (const float*)d_in[10];
    const float* exp_g1 = (const float*)d_in[11];
    const float* exp_be1 = (const float*)d_in[12];
    const float* exp_W2 = (const float*)d_in[13];
    const float* exp_b2 = (const float*)d_in[14];
    const float* gat_W  = (const float*)d_in[15];
    const float* gat_al = (const float*)d_in[16];
    const float* gat_ar = (const float*)d_in[17];
    const float* gat_b  = (const float*)d_in[18];
    const float* dec_W1 = (const float*)d_in[19];
    const float* dec_b1 = (const float*)d_in[20];
    const float* dec_g  = (const float*)d_in[21];
    const float* dec_be = (const float*)d_in[22];
    const float* dec_W2 = (const float*)d_in[23];
    const float* dec_b2 = (const float*)d_in[24];
    const float* spd_W1 = (const float*)d_in[25];
    const float* spd_b1 = (const float*)d_in[26];
    const float* spd_g  = (const float*)d_in[27];
    const float* spd_be = (const float*)d_in[28];
    const float* spd_W2 = (const float*)d_in[29];
    const float* spd_b2 = (const float*)d_in[30];
    (void)in_sizes; (void)n_in; (void)ws_size; (void)out_size;

    float* ws = (float*)d_ws;
    size_t off = 0;
    auto alloc = [&](size_t nfl) { float* p = ws + off; off += (nfl + 3) & ~(size_t)3; return p; };
    float* hA   = alloc((size_t)NN * HD);
    float* hB   = alloc((size_t)NN * HD);
    float* t1   = alloc((size_t)NN * TOPK * HD);     // also decoder t_dec
    float* eo   = alloc((size_t)NN * TOPK * HD);     // also decoder rec
    float* fbuf = alloc((size_t)NN * NHEADS * HD);
    float* el   = alloc(NN * NHEADS);
    float* er   = alloc(NN * NHEADS);
    float* pab  = alloc((size_t)2 * NN * HD);
    float* cross = alloc((size_t)NN * NN);
    float* Svec = alloc(2 * NN);
    float* Qvec = alloc(2 * NN);
    float* topw = alloc(NN * TOPK);
    float* rec_part = alloc(2 * NMASK + 4);
    float* spd_part = alloc(8 * NN);
    int* topi    = (int*)alloc(NN * TOPK);
    int* ecnt    = (int*)alloc(16);
    int* estart  = (int*)alloc(16);
    int* posArr  = (int*)alloc(NN * TOPK);
    int* eofpos  = (int*)alloc(NN * TOPK);
    int* rowlist = (int*)alloc(NN * TOPK);
    int* dec_rs  = (int*)alloc(4);
    int* nstart  = (int*)alloc(NN + 4);
    int* esorted = (int*)alloc(EE);
    int* counts    = (int*)alloc((size_t)NCHUNK * NN);
    int* chunkbase = (int*)alloc((size_t)NCHUNK * NN);
    // bf16 buffers (ushort) — sizes in floats = half the ushort count
    ushort* xm_bf  = (ushort*)alloc((size_t)NN * HD / 2);
    ushort* eh_bf  = (ushort*)alloc((size_t)NN * TOPK * HD / 2);  // also decoder zz_bf
    ushort* hA_bf  = (ushort*)alloc((size_t)NN * HD / 2);
    ushort* hB_bf  = (ushort*)alloc((size_t)NN * HD / 2);
    ushort* pp_bf  = (ushort*)alloc((size_t)2 * NN * HD / 2);
    ushort* expW1t = (ushort*)alloc((size_t)NEXPERT * HD * HD / 2);
    ushort* expW2t = (ushort*)alloc((size_t)NEXPERT * HD * HD / 2);
    ushort* gatWt  = (ushort*)alloc((size_t)NLAYER * NHEADS * HD * HD / 2);
    ushort* spdW1t = (ushort*)alloc((size_t)2 * HD * HD / 2);
    ushort* decW1t = (ushort*)alloc((size_t)2 * HD * HD / 2);
    ushort* decW2t = (ushort*)alloc((size_t)2 * HD * HD / 2);

    // all weight transposes in one launch
    k_transpose_all<<<dim3(19584), dim3(256), 0, stream>>>(
        exp_W1, exp_W2, gat_W, spd_W1, dec_W1, dec_W2,
        expW1t, expW2t, gatWt, spdW1t, decW1t, decW2t);

    // xm (masked, bf16) + gate fused
    k_xm_gate<<<dim3(NN), dim3(256), 0, stream>>>(
        feat_text, feat_image, mask_idx, mask_token, xm_bf, gate_W, gate_b, topi, topw);
    k_moe_meta<<<dim3(1), dim3(256), 0, stream>>>(topi, ecnt, estart, posArr, eofpos,
                                                  rowlist, dec_rs);

    // edge counting sort (dst-stable, deterministic)
    k_hist<<<dim3(NCHUNK), dim3(256), 0, stream>>>(dst, counts);
    k_scan_all<<<dim3(1), dim3(NN), 0, stream>>>(counts, chunkbase, nstart);
    k_rank2<<<dim3(NCHUNK), dim3(256), 0, stream>>>(dst, chunkbase, nstart, esorted);

    // experts
    k_mfma_gemm<<<dim3(HD / 64, 12, NEXPERT), dim3(256), 0, stream>>>(
        xm_bf, expW1t, t1, 0, HD, HD, HD, (long)HD * HD, 0, rowlist, ecnt, estart);
    k_ln_gelu<<<dim3(NN * TOPK), dim3(256), 0, stream>>>(t1, eh_bf, exp_b1, exp_g1, exp_be1, eofpos);
    k_mfma_gemm<<<dim3(HD / 64, 12, NEXPERT), dim3(256), 0, stream>>>(
        eh_bf, expW2t, eo, 0, HD, HD, HD, (long)HD * HD, 0, nullptr, ecnt, estart);
    k_combine_moe<<<dim3(NN), dim3(256), 0, stream>>>(eo, exp_b2, topi, topw, posArr, hA, hA_bf);

    // GAT layers
    float* hcur = hA; float* hnxt = hB;
    ushort* hcur_bf = hA_bf; ushort* hnxt_bf = hB_bf;
    for (int l = 0; l < NLAYER; l++) {
        k_mfma_gemm<<<dim3(NHEADS * HD / 64, NN / 64, 1), dim3(256), 0, stream>>>(
            hcur_bf, gatWt + (size_t)l * NHEADS * HD * HD, fbuf,
            NN, HD, HD, NHEADS * HD, 0, 0, nullptr, nullptr, nullptr);
        k_el_er<<<dim3(NN), dim3(256), 0, stream>>>(
            fbuf, gat_al + (size_t)l * NHEADS * HD, gat_ar + (size_t)l * NHEADS * HD, el, er);
        k_gat_agg<<<dim3(NN), dim3(256), 0, stream>>>(
            fbuf, el, er, src, esorted, nstart, gat_b + (size_t)l * NHEADS * HD, hnxt, hnxt_bf);
        float* t = hcur; hcur = hnxt; hnxt = t;
        ushort* tb = hcur_bf; hcur_bf = hnxt_bf; hnxt_bf = tb;
    }

    // decoder recon loss (gather fused into GEMM via rowsA)
    k_mfma_gemm<<<dim3(HD / 64, 1, 2), dim3(256), 0, stream>>>(
        hcur_bf, decW1t, t1, NMASK, HD, HD, HD, (long)HD * HD, (long)NMASK * HD,
        mask_idx, nullptr, nullptr);
    k_ln_gelu_dec<<<dim3(NMASK, 2), dim3(256), 0, stream>>>(t1, eh_bf, dec_b1, dec_g, dec_be);
    k_mfma_gemm<<<dim3(HD / 64, 1, 2), dim3(256), 0, stream>>>(
        eh_bf, decW2t, eo, NMASK, HD, HD, HD, (long)HD * HD, 0,
        nullptr, nullptr, dec_rs);
    k_cos<<<dim3(2 * NMASK), dim3(256), 0, stream>>>(
        eo, dec_b2, mask_idx, feat_text, feat_image, rec_part);

    // SPD: projections -> prep (fold b1, stats, bf16) -> cross GEMM -> loss
    k_mfma_gemm<<<dim3(HD / 64, NN / 64, 2), dim3(256), 0, stream>>>(
        hcur_bf, spdW1t, pab, NN, HD, HD, HD, (long)HD * HD, (long)NN * HD,
        nullptr, nullptr, nullptr);
    k_spd_prep<<<dim3(2 * NN), dim3(256), 0, stream>>>(pab, spd_b1, pp_bf, Svec, Qvec);
    k_mfma_gemm<<<dim3(NN / 64, NN / 64, 1), dim3(256), 0, stream>>>(
        pp_bf, pp_bf + (size_t)NN * HD, cross, NN, HD, HD, NN, 0, 0,
        nullptr, nullptr, nullptr);
    k_spd2<<<dim3(NN, 8), dim3(256), 0, stream>>>(
        pab, Svec, Qvec, cross, spd_g, spd_be, spd_W2, spd_b2, spd_matrix, spd_part);

    // output: copy h + final loss
    k_out<<<dim3(NN * HD / 256 + 1), dim3(256), 0, stream>>>(
        hcur, rec_part, spd_part, (float*)d_out);
}